// Round 2
// baseline (632.324 us; speedup 1.0000x reference)
//
#include <hip/hip_runtime.h>
#include <hip/hip_bf16.h>
#include <math.h>

// Problem constants
#define NB    2
#define CIN   256
#define CB    128
#define HH    100
#define WW    100
#define NPIX  10000       // H*W
#define CH1   640         // 128 (cur) + 512 (ltrb)
#define K2    640         // final GEMM K
#define O2    256         // final GEMM M (output channels)

// ---------------------------------------------------------------------------
// GEMM1: raw[n][ch][pix] = sum_c Wcat[ch][c] * feature[n][c][pix]
// (conv biases omitted: constant-per-channel bias is exactly cancelled by
//  instance norm's mean subtraction)
// 128x128 block tile, 8x8 per-thread micro tile, K-chunks of 16.
// Epilogue: per-channel sum / sumsq reduced across the block's 128 pixels and
// atomically accumulated into st[chan*2 +{0,1}] (instance-norm stats fusion).
// Zero-padded tail pixels contribute exact 0 to both sums -> no masking.
// ---------------------------------------------------------------------------
__global__ __launch_bounds__(256) void gemm1_k(const float* __restrict__ feat,
                                               const float* __restrict__ wcur,
                                               const float* __restrict__ wltrb,
                                               float* __restrict__ raw,
                                               float* __restrict__ st) {
    __shared__ float As[16][132];   // [k][ch]
    __shared__ float Bs[16][132];   // [k][pix]
    const int pix0 = blockIdx.x * 128;
    const int by   = blockIdx.y;            // 0..4 -> ch0 = by*128
    const int n    = blockIdx.z;
    const float* A = (by == 0) ? wcur : (wltrb + (size_t)(by - 1) * 128 * CIN);
    const float* B = feat + (size_t)n * CIN * NPIX;
    const int tid = threadIdx.x;
    const int tx = tid & 15, ty = tid >> 4;

    float acc[8][8];
#pragma unroll
    for (int i = 0; i < 8; ++i)
#pragma unroll
        for (int j = 0; j < 8; ++j) acc[i][j] = 0.f;

    for (int kc = 0; kc < CIN; kc += 16) {
        {   // stage A (transpose): As[c][r] = A[r][kc+c]
            const int c = tid & 15, r0 = tid >> 4;
#pragma unroll
            for (int i = 0; i < 8; ++i) {
                const int r = r0 + i * 16;
                As[c][r] = A[(size_t)r * CIN + kc + c];
            }
        }
        {   // stage B (direct): Bs[k][j] = B[kc+k][pix0+j]
            const int j = tid & 127, k0 = tid >> 7;
#pragma unroll
            for (int i = 0; i < 8; ++i) {
                const int k = k0 + i * 2;
                const int pix = pix0 + j;
                Bs[k][j] = (pix < NPIX) ? B[(size_t)(kc + k) * NPIX + pix] : 0.f;
            }
        }
        __syncthreads();
#pragma unroll
        for (int k = 0; k < 16; ++k) {
            float a[8], b[8];
#pragma unroll
            for (int i = 0; i < 8; ++i) a[i] = As[k][ty * 8 + i];
#pragma unroll
            for (int j = 0; j < 8; ++j) b[j] = Bs[k][tx * 8 + j];
#pragma unroll
            for (int i = 0; i < 8; ++i)
#pragma unroll
                for (int j = 0; j < 8; ++j) acc[i][j] = fmaf(a[i], b[j], acc[i][j]);
        }
        __syncthreads();
    }

    // ---- fused instance-norm stats ----
    // threads with the same ty (16 consecutive lanes, 16-aligned group within a
    // wave) hold the same 8 channels over different pixels -> 16-wide butterfly.
    {
        float s[8], q[8];
#pragma unroll
        for (int i = 0; i < 8; ++i) {
            float si = 0.f, qi = 0.f;
#pragma unroll
            for (int j = 0; j < 8; ++j) { si += acc[i][j]; qi += acc[i][j] * acc[i][j]; }
            s[i] = si; q[i] = qi;
        }
#pragma unroll
        for (int o = 1; o < 16; o <<= 1) {
#pragma unroll
            for (int i = 0; i < 8; ++i) {
                s[i] += __shfl_xor(s[i], o);
                q[i] += __shfl_xor(q[i], o);
            }
        }
        if (tx == 0) {
            const int gch0 = n * CH1 + by * 128 + ty * 8;
#pragma unroll
            for (int i = 0; i < 8; ++i) {
                atomicAdd(&st[(size_t)(gch0 + i) * 2],     s[i]);
                atomicAdd(&st[(size_t)(gch0 + i) * 2 + 1], q[i]);
            }
        }
    }

    // store raw[n][ch][pix]
    const int ch0 = by * 128;
    const int pbase = pix0 + tx * 8;
#pragma unroll
    for (int i = 0; i < 8; ++i) {
        const int ch = ch0 + ty * 8 + i;
        float* dst = raw + ((size_t)n * CH1 + ch) * NPIX + pbase;
        if (pbase + 7 < NPIX) {
            *(float4*)dst       = make_float4(acc[i][0], acc[i][1], acc[i][2], acc[i][3]);
            *(float4*)(dst + 4) = make_float4(acc[i][4], acc[i][5], acc[i][6], acc[i][7]);
        } else {
#pragma unroll
            for (int j = 0; j < 8; ++j)
                if (pbase + j < NPIX) dst[j] = acc[i][j];
        }
    }
}

// ---------------------------------------------------------------------------
// Normalize + relu + transpose to channel-last:
//   ch in [0,128)   -> CAT slot 4 (fm_short)    [n][4][pix][128]
//   ch in [128,640) -> L[n][border][pix][128]   (border = (ch-128)>>7)
// Tile: 128 ch x 64 pix via LDS. mean/rstd finalized inline from fused sums.
// ---------------------------------------------------------------------------
__global__ __launch_bounds__(256) void norm_k(const float* __restrict__ raw,
                                              const float* __restrict__ st,
                                              float* __restrict__ L,
                                              float* __restrict__ CAT) {
    __shared__ float T[128][65];
    const int pix0 = blockIdx.x * 64;
    const int chb  = blockIdx.y;             // 0..4
    const int n    = blockIdx.z;
    const int tid  = threadIdx.x;
    {
        const int pl = tid & 63, cl0 = tid >> 6;   // cl0: 0..3
#pragma unroll
        for (int i = 0; i < 32; ++i) {
            const int cl = cl0 + i * 4;
            const int gidx = n * CH1 + chb * 128 + cl;
            const float sum = st[(size_t)gidx * 2];
            const float sq  = st[(size_t)gidx * 2 + 1];
            const float m = sum * (1.0f / (float)NPIX);
            const float var = fmaxf(sq * (1.0f / (float)NPIX) - m * m, 0.f);
            const float r = 1.0f / sqrtf(var + 1e-5f);
            const int pix = pix0 + pl;
            float v = (pix < NPIX) ? raw[(size_t)gidx * NPIX + pix] : 0.f;
            v = (v - m) * r;
            T[cl][pl] = fmaxf(v, 0.f);
        }
    }
    __syncthreads();
    float* dstbase = (chb == 0)
        ? (CAT + ((size_t)(n * 5 + 4) * NPIX) * 128)
        : (L   + ((size_t)(n * 4 + (chb - 1)) * NPIX) * 128);
    const int cl = tid & 127, pl0 = tid >> 7;      // pl0: 0..1
#pragma unroll
    for (int j = 0; j < 32; ++j) {
        const int pp = pl0 + j * 2;
        const int pix = pix0 + pp;
        if (pix < NPIX) dstbase[(size_t)pix * 128 + cl] = T[cl][pp];
    }
}

// ---------------------------------------------------------------------------
// Border align: one block (128 threads = 128 channels) per (n, box, border).
// Writes CAT slots 0..3 at flat index m = 4*p + b  (matches the torch
// permute+reshape channel shuffle after permuting w_out's K dim).
// mmcv bilinear_interpolate semantics; coordinate math forced to
// unfused mul/add to match the reference's floor() decisions exactly.
// ---------------------------------------------------------------------------
__global__ __launch_bounds__(128) void border_k(const float* __restrict__ boxes,
                                                const float* __restrict__ L,
                                                float* __restrict__ CAT) {
    const int blk = blockIdx.x;                   // 0 .. 2*40000-1
    const int n = blk / 40000;
    const int m = blk % 40000;
    const int p = m >> 2, b = m & 3;
    const float* bx = boxes + ((size_t)n * NPIX + p) * 4;
    const float x1 = bx[0], y1 = bx[1], x2 = bx[2], y2 = bx[3];
    const float bw = __fsub_rn(x2, x1), bh = __fsub_rn(y2, y1);
    const int c = threadIdx.x;
    const float* Lb = L + ((size_t)(n * 4 + b) * NPIX) * 128 + c;
    float acc = -INFINITY;
#pragma unroll
    for (int k = 0; k <= 10; ++k) {
        const float t = __fdiv_rn((float)k, 10.0f);
        float x, y;
        if (b == 0)      { x = __fadd_rn(x1, __fmul_rn(t, bw)); y = y1; }
        else if (b == 1) { x = x1; y = __fadd_rn(y1, __fmul_rn(t, bh)); }
        else if (b == 2) { x = __fadd_rn(x1, __fmul_rn(t, bw)); y = y2; }
        else             { x = x2; y = __fadd_rn(y1, __fmul_rn(t, bh)); }
        const bool valid = (x >= -1.f) && (x <= (float)WW) && (y >= -1.f) && (y <= (float)HH);
        x = fmaxf(x, 0.f); y = fmaxf(y, 0.f);
        const float x0f = floorf(x), y0f = floorf(y);
        const bool cx = (x0f >= (float)(WW - 1));
        const bool cy = (y0f >= (float)(HH - 1));
        const int ix0 = cx ? (WW - 1) : (int)x0f;
        const int iy0 = cy ? (HH - 1) : (int)y0f;
        const int ix1 = min(ix0 + 1, WW - 1);
        const int iy1 = min(iy0 + 1, HH - 1);
        const float lx = cx ? 0.f : __fsub_rn(x, (float)ix0);
        const float ly = cy ? 0.f : __fsub_rn(y, (float)iy0);
        const float hx = 1.f - lx, hy = 1.f - ly;
        const float v00 = Lb[(size_t)(iy0 * WW + ix0) * 128];
        const float v01 = Lb[(size_t)(iy0 * WW + ix1) * 128];
        const float v10 = Lb[(size_t)(iy1 * WW + ix0) * 128];
        const float v11 = Lb[(size_t)(iy1 * WW + ix1) * 128];
        float v = hy * hx * v00 + hy * lx * v01 + ly * hx * v10 + ly * lx * v11;
        v = valid ? v : 0.f;
        acc = fmaxf(acc, v);
    }
    CAT[((size_t)n * 5 * NPIX + m) * 128 + c] = acc;
}

// ---------------------------------------------------------------------------
// GEMM2: out[n][o][pix] = relu(b_out[o] + sum_k W2[o][k] * CATk[n][k][pix])
// where W2[o][k] = w_out[o][perm(k)], perm(k) = (k<512) ? (k&127)*4+(k>>7) : k
// (the torch permute+reshape channel shuffle folded into the weight), and
// CATk[n][k][pix] = CAT[n][k>>7][pix][k&127] (channel-last; LDS transpose).
// ---------------------------------------------------------------------------
__global__ __launch_bounds__(256) void gemm2_k(const float* __restrict__ wout,
                                               const float* __restrict__ CAT,
                                               const float* __restrict__ bout,
                                               float* __restrict__ out) {
    __shared__ float As[16][132];   // [k][o]
    __shared__ float Bs[16][132];   // [k][pix]
    const int pix0 = blockIdx.x * 128;
    const int o0   = blockIdx.y * 128;
    const int n    = blockIdx.z;
    const float* CATn = CAT + (size_t)n * 5 * NPIX * 128;
    const int tid = threadIdx.x;
    const int tx = tid & 15, ty = tid >> 4;

    float acc[8][8];
#pragma unroll
    for (int i = 0; i < 8; ++i)
#pragma unroll
        for (int j = 0; j < 8; ++j) acc[i][j] = 0.f;

    for (int kc = 0; kc < K2; kc += 16) {
        {   // stage A with inline K-permutation: As[c][r] = wout[o0+r][perm(kc+c)]
            const int c = tid & 15, r0 = tid >> 4;
            const int k = kc + c;
            const int korig = (k < 512) ? ((k & 127) * 4 + (k >> 7)) : k;
#pragma unroll
            for (int i = 0; i < 8; ++i) {
                const int r = r0 + i * 16;
                As[c][r] = wout[(size_t)(o0 + r) * K2 + korig];
            }
        }
        {   // stage B (transpose): Bs[c][r] = CAT[n][kc>>7][pix0+r][(kc&127)+c]
            const int s = kc >> 7, c0 = kc & 127;
            const float* src = CATn + ((size_t)s * NPIX + pix0) * 128 + c0;
            const int c = tid & 15, r0 = tid >> 4;
#pragma unroll
            for (int i = 0; i < 8; ++i) {
                const int r = r0 + i * 16;
                Bs[c][r] = (pix0 + r < NPIX) ? src[(size_t)r * 128 + c] : 0.f;
            }
        }
        __syncthreads();
#pragma unroll
        for (int k = 0; k < 16; ++k) {
            float a[8], b[8];
#pragma unroll
            for (int i = 0; i < 8; ++i) a[i] = As[k][ty * 8 + i];
#pragma unroll
            for (int j = 0; j < 8; ++j) b[j] = Bs[k][tx * 8 + j];
#pragma unroll
            for (int i = 0; i < 8; ++i)
#pragma unroll
                for (int j = 0; j < 8; ++j) acc[i][j] = fmaf(a[i], b[j], acc[i][j]);
        }
        __syncthreads();
    }
    const int pbase = pix0 + tx * 8;
#pragma unroll
    for (int i = 0; i < 8; ++i) {
        const int o = o0 + ty * 8 + i;
        const float bia = bout[o];
        float* dst = out + ((size_t)n * O2 + o) * NPIX + pbase;
        if (pbase + 7 < NPIX) {
            *(float4*)dst = make_float4(fmaxf(acc[i][0] + bia, 0.f), fmaxf(acc[i][1] + bia, 0.f),
                                        fmaxf(acc[i][2] + bia, 0.f), fmaxf(acc[i][3] + bia, 0.f));
            *(float4*)(dst + 4) = make_float4(fmaxf(acc[i][4] + bia, 0.f), fmaxf(acc[i][5] + bia, 0.f),
                                              fmaxf(acc[i][6] + bia, 0.f), fmaxf(acc[i][7] + bia, 0.f));
        } else {
#pragma unroll
            for (int j = 0; j < 8; ++j)
                if (pbase + j < NPIX) dst[j] = fmaxf(acc[i][j] + bia, 0.f);
        }
    }
}

// ---------------------------------------------------------------------------
extern "C" void kernel_launch(void* const* d_in, const int* in_sizes, int n_in,
                              void* d_out, int out_size, void* d_ws, size_t ws_size,
                              hipStream_t stream) {
    const float* feature = (const float*)d_in[0];   // [2,256,100,100]
    const float* boxes   = (const float*)d_in[1];   // [2,10000,4]
    // d_in[2] = wh (unused by the reference)
    const float* w_cur   = (const float*)d_in[3];   // [128,256]
    // d_in[4] = b_cur  (cancelled by instance norm)
    const float* w_ltrb  = (const float*)d_in[5];   // [512,256]
    // d_in[6] = b_ltrb (cancelled by instance norm)
    const float* w_out   = (const float*)d_in[7];   // [256,640]
    const float* b_out   = (const float*)d_in[8];   // [256]
    float* out = (float*)d_out;

    float* ws  = (float*)d_ws;
    float* raw = ws;                                 // 2*640*10000      = 12,800,000 f
    float* L   = raw + (size_t)NB * CH1 * NPIX;      // 2*4*10000*128   = 10,240,000 f
    float* CAT = L   + (size_t)NB * 4 * NPIX * 128;  // 2*5*10000*128   = 12,800,000 f
    float* st  = CAT + (size_t)NB * 5 * NPIX * 128;  // 2*640*2         = 2,560 f

    const int pix_tiles = (NPIX + 127) / 128;        // 79

    hipMemsetAsync(st, 0, (size_t)NB * CH1 * 2 * sizeof(float), stream);
    gemm1_k<<<dim3(pix_tiles, 5, NB), 256, 0, stream>>>(feature, w_cur, w_ltrb, raw, st);
    norm_k<<<dim3((NPIX + 63) / 64, 5, NB), 256, 0, stream>>>(raw, st, L, CAT);
    border_k<<<NB * 40000, 128, 0, stream>>>(boxes, L, CAT);
    gemm2_k<<<dim3(pix_tiles, 2, NB), 256, 0, stream>>>(w_out, CAT, b_out, out);
}

// Round 3
// 526.161 us; speedup vs baseline: 1.2018x; 1.2018x over previous
//
#include <hip/hip_runtime.h>
#include <hip/hip_bf16.h>
#include <math.h>

// Problem constants
#define NB    2
#define CIN   256
#define CB    128
#define HH    100
#define WW    100
#define NPIX  10000       // H*W
#define CH1   640         // 128 (cur) + 512 (ltrb)
#define K2    640         // final GEMM K
#define O2    256         // final GEMM M (output channels)

#define FMA4(dst, s, v) do { (dst).x = fmaf((s), (v).x, (dst).x); \
                             (dst).y = fmaf((s), (v).y, (dst).y); \
                             (dst).z = fmaf((s), (v).z, (dst).z); \
                             (dst).w = fmaf((s), (v).w, (dst).w); } while (0)

// ---------------------------------------------------------------------------
// GEMM1: raw[n][ch][pix] = sum_c Wcat[ch][c] * feature[n][c][pix]
// (conv biases omitted: cancelled exactly by instance-norm mean subtraction)
// 128x128 tile, 256 thr. Quadrant-float4 micro-tile: thread (tx,ty) owns
// ch {4ty+d, 64+4ty+d} x pix {4tx+d, 64+4tx+d} -> all inner LDS reads are
// ds_read_b128 with 16 lanes spanning 32 banks (2-way = free).
// Epilogue: fused instance-norm sum/sumsq via 16-lane butterfly + atomics.
// ---------------------------------------------------------------------------
__global__ __launch_bounds__(256) void gemm1_k(const float* __restrict__ feat,
                                               const float* __restrict__ wcur,
                                               const float* __restrict__ wltrb,
                                               float* __restrict__ raw,
                                               float* __restrict__ st) {
    __shared__ float As[16][132];   // [k][ch]
    __shared__ float Bs[16][132];   // [k][pix]
    const int pix0 = blockIdx.x * 128;
    const int by   = blockIdx.y;            // 0..4 -> ch0 = by*128
    const int n    = blockIdx.z;
    const float* A = (by == 0) ? wcur : (wltrb + (size_t)(by - 1) * 128 * CIN);
    const float* B = feat + (size_t)n * CIN * NPIX;
    const int tid = threadIdx.x;
    const int tx = tid & 15, ty = tid >> 4;

    float4 acc[2][2][4];   // [chGrp][pixGrp][di] ; float4 spans 4 pix (dj)
#pragma unroll
    for (int g = 0; g < 2; ++g)
#pragma unroll
        for (int h = 0; h < 2; ++h)
#pragma unroll
            for (int d = 0; d < 4; ++d) acc[g][h][d] = make_float4(0.f, 0.f, 0.f, 0.f);

    for (int kc = 0; kc < CIN; kc += 16) {
        {   // stage A (transpose): As[c][r] = A[r][kc+c]
            const int c = tid & 15, r0 = tid >> 4;
#pragma unroll
            for (int i = 0; i < 8; ++i) {
                const int r = r0 + i * 16;
                As[c][r] = A[(size_t)r * CIN + kc + c];
            }
        }
        {   // stage B (direct, float4): Bs[k][j4..j4+3] = B[kc+k][pix0+j4..]
            const int j4 = (tid & 31) * 4;
            const int k0 = tid >> 5;
#pragma unroll
            for (int kk = 0; kk < 2; ++kk) {
                const int k = k0 + kk * 8;
                const int pix = pix0 + j4;
                float4 v = (pix < NPIX) ? *(const float4*)&B[(size_t)(kc + k) * NPIX + pix]
                                        : make_float4(0.f, 0.f, 0.f, 0.f);
                *(float4*)&Bs[k][j4] = v;
            }
        }
        __syncthreads();
#pragma unroll
        for (int k = 0; k < 16; ++k) {
            const float4 a0 = *(const float4*)&As[k][4 * ty];
            const float4 a1 = *(const float4*)&As[k][64 + 4 * ty];
            const float4 b0 = *(const float4*)&Bs[k][4 * tx];
            const float4 b1 = *(const float4*)&Bs[k][64 + 4 * tx];
            FMA4(acc[0][0][0], a0.x, b0); FMA4(acc[0][0][1], a0.y, b0);
            FMA4(acc[0][0][2], a0.z, b0); FMA4(acc[0][0][3], a0.w, b0);
            FMA4(acc[0][1][0], a0.x, b1); FMA4(acc[0][1][1], a0.y, b1);
            FMA4(acc[0][1][2], a0.z, b1); FMA4(acc[0][1][3], a0.w, b1);
            FMA4(acc[1][0][0], a1.x, b0); FMA4(acc[1][0][1], a1.y, b0);
            FMA4(acc[1][0][2], a1.z, b0); FMA4(acc[1][0][3], a1.w, b0);
            FMA4(acc[1][1][0], a1.x, b1); FMA4(acc[1][1][1], a1.y, b1);
            FMA4(acc[1][1][2], a1.z, b1); FMA4(acc[1][1][3], a1.w, b1);
        }
        __syncthreads();
    }

    // ---- fused instance-norm stats (zero-padded tail contributes exact 0) ----
    {
#pragma unroll
        for (int g = 0; g < 2; ++g)
#pragma unroll
            for (int d = 0; d < 4; ++d) {
                const float4 p0 = acc[g][0][d], p1 = acc[g][1][d];
                float s = p0.x + p0.y + p0.z + p0.w + p1.x + p1.y + p1.z + p1.w;
                float q = p0.x * p0.x + p0.y * p0.y + p0.z * p0.z + p0.w * p0.w
                        + p1.x * p1.x + p1.y * p1.y + p1.z * p1.z + p1.w * p1.w;
#pragma unroll
                for (int o = 1; o < 16; o <<= 1) {
                    s += __shfl_xor(s, o);
                    q += __shfl_xor(q, o);
                }
                if (tx == 0) {
                    const int gch = n * CH1 + by * 128 + 64 * g + 4 * ty + d;
                    atomicAdd(&st[(size_t)gch * 2],     s);
                    atomicAdd(&st[(size_t)gch * 2 + 1], q);
                }
            }
    }

    // store raw[n][ch][pix]
#pragma unroll
    for (int g = 0; g < 2; ++g)
#pragma unroll
        for (int d = 0; d < 4; ++d) {
            const int ch = by * 128 + 64 * g + 4 * ty + d;
            float* dst = raw + ((size_t)n * CH1 + ch) * NPIX;
#pragma unroll
            for (int h = 0; h < 2; ++h) {
                const int pb = pix0 + 64 * h + 4 * tx;
                if (pb < NPIX) *(float4*)&dst[pb] = acc[g][h][d];
            }
        }
}

// ---------------------------------------------------------------------------
// Normalize + relu + transpose to channel-last:
//   ch in [0,128)   -> CAT slot 4 (fm_short)    [n][4][pix][128]
//   ch in [128,640) -> L[n][border][pix][128]   (border = (ch-128)>>7)
// ---------------------------------------------------------------------------
__global__ __launch_bounds__(256) void norm_k(const float* __restrict__ raw,
                                              const float* __restrict__ st,
                                              float* __restrict__ L,
                                              float* __restrict__ CAT) {
    __shared__ float T[128][65];
    const int pix0 = blockIdx.x * 64;
    const int chb  = blockIdx.y;             // 0..4
    const int n    = blockIdx.z;
    const int tid  = threadIdx.x;
    {
        const int pl = tid & 63, cl0 = tid >> 6;   // cl0: 0..3
#pragma unroll
        for (int i = 0; i < 32; ++i) {
            const int cl = cl0 + i * 4;
            const int gidx = n * CH1 + chb * 128 + cl;
            const float sum = st[(size_t)gidx * 2];
            const float sq  = st[(size_t)gidx * 2 + 1];
            const float m = sum * (1.0f / (float)NPIX);
            const float var = fmaxf(sq * (1.0f / (float)NPIX) - m * m, 0.f);
            const float r = 1.0f / sqrtf(var + 1e-5f);
            const int pix = pix0 + pl;
            float v = (pix < NPIX) ? raw[(size_t)gidx * NPIX + pix] : 0.f;
            v = (v - m) * r;
            T[cl][pl] = fmaxf(v, 0.f);
        }
    }
    __syncthreads();
    float* dstbase = (chb == 0)
        ? (CAT + ((size_t)(n * 5 + 4) * NPIX) * 128)
        : (L   + ((size_t)(n * 4 + (chb - 1)) * NPIX) * 128);
    const int cl = tid & 127, pl0 = tid >> 7;      // pl0: 0..1
#pragma unroll
    for (int j = 0; j < 32; ++j) {
        const int pp = pl0 + j * 2;
        const int pix = pix0 + pp;
        if (pix < NPIX) dstbase[(size_t)pix * 128 + cl] = T[cl][pp];
    }
}

// ---------------------------------------------------------------------------
// Border align: one block (128 threads = 128 channels) per (n, box, border).
// Writes CAT slots 0..3 at flat index m = 4*p + b (torch permute folded into
// gemm2's weight indexing). mmcv bilinear semantics; unfused coord math.
// ---------------------------------------------------------------------------
__global__ __launch_bounds__(128) void border_k(const float* __restrict__ boxes,
                                                const float* __restrict__ L,
                                                float* __restrict__ CAT) {
    const int blk = blockIdx.x;                   // 0 .. 2*40000-1
    const int n = blk / 40000;
    const int m = blk % 40000;
    const int p = m >> 2, b = m & 3;
    const float* bx = boxes + ((size_t)n * NPIX + p) * 4;
    const float x1 = bx[0], y1 = bx[1], x2 = bx[2], y2 = bx[3];
    const float bw = __fsub_rn(x2, x1), bh = __fsub_rn(y2, y1);
    const int c = threadIdx.x;
    const float* Lb = L + ((size_t)(n * 4 + b) * NPIX) * 128 + c;
    float acc = -INFINITY;
#pragma unroll
    for (int k = 0; k <= 10; ++k) {
        const float t = __fdiv_rn((float)k, 10.0f);
        float x, y;
        if (b == 0)      { x = __fadd_rn(x1, __fmul_rn(t, bw)); y = y1; }
        else if (b == 1) { x = x1; y = __fadd_rn(y1, __fmul_rn(t, bh)); }
        else if (b == 2) { x = __fadd_rn(x1, __fmul_rn(t, bw)); y = y2; }
        else             { x = x2; y = __fadd_rn(y1, __fmul_rn(t, bh)); }
        const bool valid = (x >= -1.f) && (x <= (float)WW) && (y >= -1.f) && (y <= (float)HH);
        x = fmaxf(x, 0.f); y = fmaxf(y, 0.f);
        const float x0f = floorf(x), y0f = floorf(y);
        const bool cx = (x0f >= (float)(WW - 1));
        const bool cy = (y0f >= (float)(HH - 1));
        const int ix0 = cx ? (WW - 1) : (int)x0f;
        const int iy0 = cy ? (HH - 1) : (int)y0f;
        const int ix1 = min(ix0 + 1, WW - 1);
        const int iy1 = min(iy0 + 1, HH - 1);
        const float lx = cx ? 0.f : __fsub_rn(x, (float)ix0);
        const float ly = cy ? 0.f : __fsub_rn(y, (float)iy0);
        const float hx = 1.f - lx, hy = 1.f - ly;
        const float v00 = Lb[(size_t)(iy0 * WW + ix0) * 128];
        const float v01 = Lb[(size_t)(iy0 * WW + ix1) * 128];
        const float v10 = Lb[(size_t)(iy1 * WW + ix0) * 128];
        const float v11 = Lb[(size_t)(iy1 * WW + ix1) * 128];
        float v = hy * hx * v00 + hy * lx * v01 + ly * hx * v10 + ly * lx * v11;
        v = valid ? v : 0.f;
        acc = fmaxf(acc, v);
    }
    CAT[((size_t)n * 5 * NPIX + m) * 128 + c] = acc;
}

// ---------------------------------------------------------------------------
// GEMM2: out[n][o][pix] = relu(b_out[o] + sum_k wout[o][perm(k)] * CATk)
// perm(k) = (k<512) ? (k&127)*4+(k>>7) : k   (torch permute+reshape folded in)
// CATk[n][k][pix] = CAT[n][k>>7][pix][k&127]  (channel-last source).
// Tile 128(o) x 64(pix), 256 thr -> grid 157*2*2 = 628 blocks.
// ---------------------------------------------------------------------------
__global__ __launch_bounds__(256) void gemm2_k(const float* __restrict__ wout,
                                               const float* __restrict__ CAT,
                                               const float* __restrict__ bout,
                                               float* __restrict__ out) {
    __shared__ float As[16][132];   // [k][o]
    __shared__ float Bs[16][68];    // [k][pix]
    const int pix0 = blockIdx.x * 64;
    const int o0   = blockIdx.y * 128;
    const int n    = blockIdx.z;
    const float* CATn = CAT + (size_t)n * 5 * NPIX * 128;
    const int tid = threadIdx.x;
    const int tx = tid & 15, ty = tid >> 4;

    float4 acc[2][4];   // [oGrp][di] ; float4 spans 4 pix
#pragma unroll
    for (int g = 0; g < 2; ++g)
#pragma unroll
        for (int d = 0; d < 4; ++d) acc[g][d] = make_float4(0.f, 0.f, 0.f, 0.f);

    for (int kc = 0; kc < K2; kc += 16) {
        {   // stage A with inline K-permutation: As[c][r] = wout[o0+r][perm(kc+c)]
            const int c = tid & 15, r0 = tid >> 4;
            const int k = kc + c;
            const int korig = (k < 512) ? ((k & 127) * 4 + (k >> 7)) : k;
#pragma unroll
            for (int i = 0; i < 8; ++i) {
                const int r = r0 + i * 16;
                As[c][r] = wout[(size_t)(o0 + r) * K2 + korig];
            }
        }
        {   // stage B (transpose via float4 read along channels)
            const int slot = kc >> 7, c0 = kc & 127;
            const int pl = tid & 63;
            const int k4 = (tid >> 6) * 4;       // 0,4,8,12 per wave
            const int pix = pix0 + pl;
            float4 v = (pix < NPIX)
                ? *(const float4*)&CATn[((size_t)slot * NPIX + pix) * 128 + c0 + k4]
                : make_float4(0.f, 0.f, 0.f, 0.f);
            Bs[k4 + 0][pl] = v.x;
            Bs[k4 + 1][pl] = v.y;
            Bs[k4 + 2][pl] = v.z;
            Bs[k4 + 3][pl] = v.w;
        }
        __syncthreads();
#pragma unroll
        for (int k = 0; k < 16; ++k) {
            const float4 a0 = *(const float4*)&As[k][4 * ty];
            const float4 a1 = *(const float4*)&As[k][64 + 4 * ty];
            const float4 b0 = *(const float4*)&Bs[k][4 * tx];
            FMA4(acc[0][0], a0.x, b0); FMA4(acc[0][1], a0.y, b0);
            FMA4(acc[0][2], a0.z, b0); FMA4(acc[0][3], a0.w, b0);
            FMA4(acc[1][0], a1.x, b0); FMA4(acc[1][1], a1.y, b0);
            FMA4(acc[1][2], a1.z, b0); FMA4(acc[1][3], a1.w, b0);
        }
        __syncthreads();
    }

    const int pb = pix0 + 4 * tx;
    if (pb < NPIX) {
#pragma unroll
        for (int g = 0; g < 2; ++g)
#pragma unroll
            for (int d = 0; d < 4; ++d) {
                const int o = o0 + 64 * g + 4 * ty + d;
                const float bia = bout[o];
                float4 v = acc[g][d];
                v.x = fmaxf(v.x + bia, 0.f);
                v.y = fmaxf(v.y + bia, 0.f);
                v.z = fmaxf(v.z + bia, 0.f);
                v.w = fmaxf(v.w + bia, 0.f);
                *(float4*)&out[((size_t)n * O2 + o) * NPIX + pb] = v;
            }
    }
}

// ---------------------------------------------------------------------------
extern "C" void kernel_launch(void* const* d_in, const int* in_sizes, int n_in,
                              void* d_out, int out_size, void* d_ws, size_t ws_size,
                              hipStream_t stream) {
    const float* feature = (const float*)d_in[0];   // [2,256,100,100]
    const float* boxes   = (const float*)d_in[1];   // [2,10000,4]
    // d_in[2] = wh (unused by the reference)
    const float* w_cur   = (const float*)d_in[3];   // [128,256]
    // d_in[4] = b_cur  (cancelled by instance norm)
    const float* w_ltrb  = (const float*)d_in[5];   // [512,256]
    // d_in[6] = b_ltrb (cancelled by instance norm)
    const float* w_out   = (const float*)d_in[7];   // [256,640]
    const float* b_out   = (const float*)d_in[8];   // [256]
    float* out = (float*)d_out;

    float* ws  = (float*)d_ws;
    float* raw = ws;                                 // 2*640*10000      = 12,800,000 f
    float* L   = raw + (size_t)NB * CH1 * NPIX;      // 2*4*10000*128   = 10,240,000 f
    float* CAT = L   + (size_t)NB * 4 * NPIX * 128;  // 2*5*10000*128   = 12,800,000 f
    float* st  = CAT + (size_t)NB * 5 * NPIX * 128;  // 2*640*2         = 2,560 f

    hipMemsetAsync(st, 0, (size_t)NB * CH1 * 2 * sizeof(float), stream);
    gemm1_k<<<dim3((NPIX + 127) / 128, 5, NB), 256, 0, stream>>>(feature, w_cur, w_ltrb, raw, st);
    norm_k<<<dim3((NPIX + 63) / 64, 5, NB), 256, 0, stream>>>(raw, st, L, CAT);
    border_k<<<NB * 40000, 128, 0, stream>>>(boxes, L, CAT);
    gemm2_k<<<dim3((NPIX + 63) / 64, 2, NB), 256, 0, stream>>>(w_out, CAT, b_out, out);
}

// Round 4
// 471.526 us; speedup vs baseline: 1.3410x; 1.1159x over previous
//
#include <hip/hip_runtime.h>
#include <hip/hip_bf16.h>
#include <math.h>

// Problem constants
#define NB    2
#define CIN   256
#define CB    128
#define HH    100
#define WW    100
#define NPIX  10000       // H*W
#define CH1   640         // 128 (cur) + 512 (ltrb)
#define K2    640         // final GEMM K
#define O2    256         // final GEMM M (output channels)
#define NM    40000       // 4 * NPIX  (flattened (box,border) units per n)
#define NSAMP 11          // POOL+1 samples per border

#define FMA4(dst, s, v) do { (dst).x = fmaf((s), (v).x, (dst).x); \
                             (dst).y = fmaf((s), (v).y, (dst).y); \
                             (dst).z = fmaf((s), (v).z, (dst).z); \
                             (dst).w = fmaf((s), (v).w, (dst).w); } while (0)

// ---------------------------------------------------------------------------
// GEMM1: raw[n][ch][pix] = sum_c Wcat[ch][c] * feature[n][c][pix]
// (conv biases omitted: cancelled exactly by instance-norm mean subtraction)
// 128x128 tile, 256 thr, quadrant-float4 micro-tile (conflict-free b128 LDS).
// Epilogue: fused instance-norm sum/sumsq via 16-lane butterfly + atomics.
// ---------------------------------------------------------------------------
__global__ __launch_bounds__(256) void gemm1_k(const float* __restrict__ feat,
                                               const float* __restrict__ wcur,
                                               const float* __restrict__ wltrb,
                                               float* __restrict__ raw,
                                               float* __restrict__ st) {
    __shared__ float As[16][132];   // [k][ch]
    __shared__ float Bs[16][132];   // [k][pix]
    const int pix0 = blockIdx.x * 128;
    const int by   = blockIdx.y;            // 0..4 -> ch0 = by*128
    const int n    = blockIdx.z;
    const float* A = (by == 0) ? wcur : (wltrb + (size_t)(by - 1) * 128 * CIN);
    const float* B = feat + (size_t)n * CIN * NPIX;
    const int tid = threadIdx.x;
    const int tx = tid & 15, ty = tid >> 4;

    float4 acc[2][2][4];   // [chGrp][pixGrp][di] ; float4 spans 4 pix (dj)
#pragma unroll
    for (int g = 0; g < 2; ++g)
#pragma unroll
        for (int h = 0; h < 2; ++h)
#pragma unroll
            for (int d = 0; d < 4; ++d) acc[g][h][d] = make_float4(0.f, 0.f, 0.f, 0.f);

    for (int kc = 0; kc < CIN; kc += 16) {
        {   // stage A (transpose): As[c][r] = A[r][kc+c]
            const int c = tid & 15, r0 = tid >> 4;
#pragma unroll
            for (int i = 0; i < 8; ++i) {
                const int r = r0 + i * 16;
                As[c][r] = A[(size_t)r * CIN + kc + c];
            }
        }
        {   // stage B (direct, float4): Bs[k][j4..j4+3] = B[kc+k][pix0+j4..]
            const int j4 = (tid & 31) * 4;
            const int k0 = tid >> 5;
#pragma unroll
            for (int kk = 0; kk < 2; ++kk) {
                const int k = k0 + kk * 8;
                const int pix = pix0 + j4;
                float4 v = (pix < NPIX) ? *(const float4*)&B[(size_t)(kc + k) * NPIX + pix]
                                        : make_float4(0.f, 0.f, 0.f, 0.f);
                *(float4*)&Bs[k][j4] = v;
            }
        }
        __syncthreads();
#pragma unroll
        for (int k = 0; k < 16; ++k) {
            const float4 a0 = *(const float4*)&As[k][4 * ty];
            const float4 a1 = *(const float4*)&As[k][64 + 4 * ty];
            const float4 b0 = *(const float4*)&Bs[k][4 * tx];
            const float4 b1 = *(const float4*)&Bs[k][64 + 4 * tx];
            FMA4(acc[0][0][0], a0.x, b0); FMA4(acc[0][0][1], a0.y, b0);
            FMA4(acc[0][0][2], a0.z, b0); FMA4(acc[0][0][3], a0.w, b0);
            FMA4(acc[0][1][0], a0.x, b1); FMA4(acc[0][1][1], a0.y, b1);
            FMA4(acc[0][1][2], a0.z, b1); FMA4(acc[0][1][3], a0.w, b1);
            FMA4(acc[1][0][0], a1.x, b0); FMA4(acc[1][0][1], a1.y, b0);
            FMA4(acc[1][0][2], a1.z, b0); FMA4(acc[1][0][3], a1.w, b0);
            FMA4(acc[1][1][0], a1.x, b1); FMA4(acc[1][1][1], a1.y, b1);
            FMA4(acc[1][1][2], a1.z, b1); FMA4(acc[1][1][3], a1.w, b1);
        }
        __syncthreads();
    }

    // ---- fused instance-norm stats (zero-padded tail contributes exact 0) ----
    {
#pragma unroll
        for (int g = 0; g < 2; ++g)
#pragma unroll
            for (int d = 0; d < 4; ++d) {
                const float4 p0 = acc[g][0][d], p1 = acc[g][1][d];
                float s = p0.x + p0.y + p0.z + p0.w + p1.x + p1.y + p1.z + p1.w;
                float q = p0.x * p0.x + p0.y * p0.y + p0.z * p0.z + p0.w * p0.w
                        + p1.x * p1.x + p1.y * p1.y + p1.z * p1.z + p1.w * p1.w;
#pragma unroll
                for (int o = 1; o < 16; o <<= 1) {
                    s += __shfl_xor(s, o);
                    q += __shfl_xor(q, o);
                }
                if (tx == 0) {
                    const int gch = n * CH1 + by * 128 + 64 * g + 4 * ty + d;
                    atomicAdd(&st[(size_t)gch * 2],     s);
                    atomicAdd(&st[(size_t)gch * 2 + 1], q);
                }
            }
    }

    // store raw[n][ch][pix]
#pragma unroll
    for (int g = 0; g < 2; ++g)
#pragma unroll
        for (int d = 0; d < 4; ++d) {
            const int ch = by * 128 + 64 * g + 4 * ty + d;
            float* dst = raw + ((size_t)n * CH1 + ch) * NPIX;
#pragma unroll
            for (int h = 0; h < 2; ++h) {
                const int pb = pix0 + 64 * h + 4 * tx;
                if (pb < NPIX) *(float4*)&dst[pb] = acc[g][h][d];
            }
        }
}

// ---------------------------------------------------------------------------
// Normalize + relu + transpose to channel-last:
//   ch in [0,128)   -> CAT slot 4 (fm_short)    [n][4][pix][128]
//   ch in [128,640) -> L[n][border][pix][128]   (border = (ch-128)>>7)
// ---------------------------------------------------------------------------
__global__ __launch_bounds__(256) void norm_k(const float* __restrict__ raw,
                                              const float* __restrict__ st,
                                              float* __restrict__ L,
                                              float* __restrict__ CAT) {
    __shared__ float T[128][65];
    const int pix0 = blockIdx.x * 64;
    const int chb  = blockIdx.y;             // 0..4
    const int n    = blockIdx.z;
    const int tid  = threadIdx.x;
    {
        const int pl = tid & 63, cl0 = tid >> 6;   // cl0: 0..3
#pragma unroll
        for (int i = 0; i < 32; ++i) {
            const int cl = cl0 + i * 4;
            const int gidx = n * CH1 + chb * 128 + cl;
            const float sum = st[(size_t)gidx * 2];
            const float sq  = st[(size_t)gidx * 2 + 1];
            const float m = sum * (1.0f / (float)NPIX);
            const float var = fmaxf(sq * (1.0f / (float)NPIX) - m * m, 0.f);
            const float r = 1.0f / sqrtf(var + 1e-5f);
            const int pix = pix0 + pl;
            float v = (pix < NPIX) ? raw[(size_t)gidx * NPIX + pix] : 0.f;
            v = (v - m) * r;
            T[cl][pl] = fmaxf(v, 0.f);
        }
    }
    __syncthreads();
    float* dstbase = (chb == 0)
        ? (CAT + ((size_t)(n * 5 + 4) * NPIX) * 128)
        : (L   + ((size_t)(n * 4 + (chb - 1)) * NPIX) * 128);
    const int cl = tid & 127, pl0 = tid >> 7;      // pl0: 0..1
#pragma unroll
    for (int j = 0; j < 32; ++j) {
        const int pp = pl0 + j * 2;
        const int pix = pix0 + pp;
        if (pix < NPIX) dstbase[(size_t)pix * 128 + cl] = T[cl][pp];
    }
}

// ---------------------------------------------------------------------------
// coord_k: one thread per (n, m=4p+b, sample k). Computes the bilinear sample
// descriptor ONCE (was duplicated across all 128 channel-lanes before):
//   OFFS = o00 | dx<<14 | dy<<15   (o00 = iy0*W+ix0, dx/dy in {0,1})
//   WTS  = (w00,w01,w10,w11) with the `valid` mask folded in (x1.0/x0.0 exact)
// mmcv bilinear semantics; coordinate arithmetic kept bit-identical to the
// previously passing version (unfused mul/add, same clamping).
// ---------------------------------------------------------------------------
__global__ __launch_bounds__(256) void coord_k(const float* __restrict__ boxes,
                                               int* __restrict__ OFFS,
                                               float4* __restrict__ WTS) {
    const int id = blockIdx.x * 256 + threadIdx.x;
    if (id >= NB * NM * NSAMP) return;
    const int k  = id % NSAMP;
    const int mm = id / NSAMP;              // n*NM + m
    const int m  = mm % NM;
    const int n  = mm / NM;
    const int p = m >> 2, b = m & 3;
    const float* bx = boxes + ((size_t)n * NPIX + p) * 4;
    const float x1 = bx[0], y1 = bx[1], x2 = bx[2], y2 = bx[3];
    const float bw = __fsub_rn(x2, x1), bh = __fsub_rn(y2, y1);
    const float t = __fdiv_rn((float)k, 10.0f);
    float x, y;
    if (b == 0)      { x = __fadd_rn(x1, __fmul_rn(t, bw)); y = y1; }
    else if (b == 1) { x = x1; y = __fadd_rn(y1, __fmul_rn(t, bh)); }
    else if (b == 2) { x = __fadd_rn(x1, __fmul_rn(t, bw)); y = y2; }
    else             { x = x2; y = __fadd_rn(y1, __fmul_rn(t, bh)); }
    const bool valid = (x >= -1.f) && (x <= (float)WW) && (y >= -1.f) && (y <= (float)HH);
    x = fmaxf(x, 0.f); y = fmaxf(y, 0.f);
    const float x0f = floorf(x), y0f = floorf(y);
    const bool cx = (x0f >= (float)(WW - 1));
    const bool cy = (y0f >= (float)(HH - 1));
    const int ix0 = cx ? (WW - 1) : (int)x0f;
    const int iy0 = cy ? (HH - 1) : (int)y0f;
    const int ix1 = min(ix0 + 1, WW - 1);
    const int iy1 = min(iy0 + 1, HH - 1);
    const float lx = cx ? 0.f : __fsub_rn(x, (float)ix0);
    const float ly = cy ? 0.f : __fsub_rn(y, (float)iy0);
    const float hx = 1.f - lx, hy = 1.f - ly;
    const float vf = valid ? 1.f : 0.f;
    const int dx = ix1 - ix0, dy = iy1 - iy0;
    OFFS[id] = (iy0 * WW + ix0) | (dx << 14) | (dy << 15);
    WTS[id]  = make_float4((hy * hx) * vf, (hy * lx) * vf,
                           (ly * hx) * vf, (ly * lx) * vf);
}

// ---------------------------------------------------------------------------
// Border gather: 256 thr = 2 (n,m) units x 128 channels. Per sample: 2 uniform
// descriptor loads + 4 coalesced 512B channel-gathers + 4 FMA + max.
// Writes CAT slots 0..3 at flat index m = 4*p + b (torch permute folded into
// gemm2's weight indexing).
// ---------------------------------------------------------------------------
__global__ __launch_bounds__(256) void border_k(const int* __restrict__ OFFS,
                                                const float4* __restrict__ WTS,
                                                const float* __restrict__ L,
                                                float* __restrict__ CAT) {
    const int half = threadIdx.x >> 7;
    const int c    = threadIdx.x & 127;
    const int mm   = blockIdx.x * 2 + half;       // n*NM + m
    const int m = mm % NM, n = mm / NM;
    const int b = m & 3;
    const float* Lb = L + ((size_t)(n * 4 + b) * NPIX) * 128 + c;
    const int base = mm * NSAMP;
    float acc = -INFINITY;
#pragma unroll
    for (int k = 0; k < NSAMP; ++k) {
        const int   v = OFFS[base + k];
        const float4 w = WTS[base + k];
        const int off = v & 0x3FFF;
        const int dxo = ((v >> 14) & 1) * 128;
        const int dyo = ((v >> 15) & 1) * (WW * 128);
        const float* p = Lb + (size_t)off * 128;
        const float g00 = p[0];
        const float g01 = p[dxo];
        const float g10 = p[dyo];
        const float g11 = p[dyo + dxo];
        const float val = w.x * g00 + w.y * g01 + w.z * g10 + w.w * g11;
        acc = fmaxf(acc, val);
    }
    CAT[((size_t)n * 5 * NPIX + m) * 128 + c] = acc;
}

// ---------------------------------------------------------------------------
// GEMM2: out[n][o][pix] = relu(b_out[o] + sum_k wout[o][perm(k)] * CATk)
// perm(k) = (k<512) ? (k&127)*4+(k>>7) : k   (torch permute+reshape folded in)
// CATk[n][k][pix] = CAT[n][k>>7][pix][k&127]  (channel-last source).
// Tile 128(o) x 64(pix), 256 thr -> grid 157*2*2 = 628 blocks.
// ---------------------------------------------------------------------------
__global__ __launch_bounds__(256) void gemm2_k(const float* __restrict__ wout,
                                               const float* __restrict__ CAT,
                                               const float* __restrict__ bout,
                                               float* __restrict__ out) {
    __shared__ float As[16][132];   // [k][o]
    __shared__ float Bs[16][68];    // [k][pix]
    const int pix0 = blockIdx.x * 64;
    const int o0   = blockIdx.y * 128;
    const int n    = blockIdx.z;
    const float* CATn = CAT + (size_t)n * 5 * NPIX * 128;
    const int tid = threadIdx.x;
    const int tx = tid & 15, ty = tid >> 4;

    float4 acc[2][4];   // [oGrp][di] ; float4 spans 4 pix
#pragma unroll
    for (int g = 0; g < 2; ++g)
#pragma unroll
        for (int d = 0; d < 4; ++d) acc[g][d] = make_float4(0.f, 0.f, 0.f, 0.f);

    for (int kc = 0; kc < K2; kc += 16) {
        {   // stage A with inline K-permutation: As[c][r] = wout[o0+r][perm(kc+c)]
            const int c = tid & 15, r0 = tid >> 4;
            const int k = kc + c;
            const int korig = (k < 512) ? ((k & 127) * 4 + (k >> 7)) : k;
#pragma unroll
            for (int i = 0; i < 8; ++i) {
                const int r = r0 + i * 16;
                As[c][r] = wout[(size_t)(o0 + r) * K2 + korig];
            }
        }
        {   // stage B (transpose via float4 read along channels)
            const int slot = kc >> 7, c0 = kc & 127;
            const int pl = tid & 63;
            const int k4 = (tid >> 6) * 4;       // 0,4,8,12 per wave
            const int pix = pix0 + pl;
            float4 v = (pix < NPIX)
                ? *(const float4*)&CATn[((size_t)slot * NPIX + pix) * 128 + c0 + k4]
                : make_float4(0.f, 0.f, 0.f, 0.f);
            Bs[k4 + 0][pl] = v.x;
            Bs[k4 + 1][pl] = v.y;
            Bs[k4 + 2][pl] = v.z;
            Bs[k4 + 3][pl] = v.w;
        }
        __syncthreads();
#pragma unroll
        for (int k = 0; k < 16; ++k) {
            const float4 a0 = *(const float4*)&As[k][4 * ty];
            const float4 a1 = *(const float4*)&As[k][64 + 4 * ty];
            const float4 b0 = *(const float4*)&Bs[k][4 * tx];
            FMA4(acc[0][0], a0.x, b0); FMA4(acc[0][1], a0.y, b0);
            FMA4(acc[0][2], a0.z, b0); FMA4(acc[0][3], a0.w, b0);
            FMA4(acc[1][0], a1.x, b0); FMA4(acc[1][1], a1.y, b0);
            FMA4(acc[1][2], a1.z, b0); FMA4(acc[1][3], a1.w, b0);
        }
        __syncthreads();
    }

    const int pb = pix0 + 4 * tx;
    if (pb < NPIX) {
#pragma unroll
        for (int g = 0; g < 2; ++g)
#pragma unroll
            for (int d = 0; d < 4; ++d) {
                const int o = o0 + 64 * g + 4 * ty + d;
                const float bia = bout[o];
                float4 v = acc[g][d];
                v.x = fmaxf(v.x + bia, 0.f);
                v.y = fmaxf(v.y + bia, 0.f);
                v.z = fmaxf(v.z + bia, 0.f);
                v.w = fmaxf(v.w + bia, 0.f);
                *(float4*)&out[((size_t)n * O2 + o) * NPIX + pb] = v;
            }
    }
}

// ---------------------------------------------------------------------------
extern "C" void kernel_launch(void* const* d_in, const int* in_sizes, int n_in,
                              void* d_out, int out_size, void* d_ws, size_t ws_size,
                              hipStream_t stream) {
    const float* feature = (const float*)d_in[0];   // [2,256,100,100]
    const float* boxes   = (const float*)d_in[1];   // [2,10000,4]
    // d_in[2] = wh (unused by the reference)
    const float* w_cur   = (const float*)d_in[3];   // [128,256]
    // d_in[4] = b_cur  (cancelled by instance norm)
    const float* w_ltrb  = (const float*)d_in[5];   // [512,256]
    // d_in[6] = b_ltrb (cancelled by instance norm)
    const float* w_out   = (const float*)d_in[7];   // [256,640]
    const float* b_out   = (const float*)d_in[8];   // [256]
    float* out = (float*)d_out;

    float* ws  = (float*)d_ws;
    float* raw = ws;                                 // 2*640*10000      = 12,800,000 f
    float* L   = raw + (size_t)NB * CH1 * NPIX;      // 2*4*10000*128   = 10,240,000 f
    float* CAT = L   + (size_t)NB * 4 * NPIX * 128;  // 2*5*10000*128   = 12,800,000 f
    float* st  = CAT + (size_t)NB * 5 * NPIX * 128;  // 2*640*2         = 2,560 f

    // Sample descriptors alias raw's space (raw is dead after norm_k).
    // 2*40000*11 = 880,000 descriptors: ints then float4s (16B-aligned).
    int*    OFFS = (int*)raw;
    float4* WTS  = (float4*)(raw + (1 << 20));       // 880k ints < 1M floats

    hipMemsetAsync(st, 0, (size_t)NB * CH1 * 2 * sizeof(float), stream);
    gemm1_k<<<dim3((NPIX + 127) / 128, 5, NB), 256, 0, stream>>>(feature, w_cur, w_ltrb, raw, st);
    norm_k<<<dim3((NPIX + 63) / 64, 5, NB), 256, 0, stream>>>(raw, st, L, CAT);
    coord_k<<<(NB * NM * NSAMP + 255) / 256, 256, 0, stream>>>(boxes, OFFS, WTS);
    border_k<<<NB * NM / 2, 256, 0, stream>>>(OFFS, WTS, L, CAT);
    gemm2_k<<<dim3((NPIX + 63) / 64, 2, NB), 256, 0, stream>>>(w_out, CAT, b_out, out);
}

// Round 5
// 388.516 us; speedup vs baseline: 1.6275x; 1.2137x over previous
//
#include <hip/hip_runtime.h>
#include <hip/hip_bf16.h>
#include <math.h>

// Problem constants
#define NB    2
#define CIN   256
#define CB    128
#define HH    100
#define WW    100
#define NPIX  10000       // H*W
#define CH1   640         // 128 (cur) + 512 (ltrb)
#define K2    640         // final GEMM K
#define O2    256         // final GEMM M (output channels)
#define NM    40000       // 4 * NPIX  (flattened (box,border) units per n)
#define NSAMP 11          // POOL+1 samples per border

typedef __attribute__((ext_vector_type(8))) short bf16x8;   // 8 bf16 = 4 VGPR
typedef __attribute__((ext_vector_type(4))) float f32x4;    // MFMA accumulator
typedef unsigned short ushort_t;

__device__ __forceinline__ unsigned short f2bf(float f) {   // RNE f32->bf16
    unsigned u = __float_as_uint(f);
    u += 0x7FFF + ((u >> 16) & 1);
    return (unsigned short)(u >> 16);
}

#define MFMA16(a, b, c) __builtin_amdgcn_mfma_f32_16x16x32_bf16((a), (b), (c), 0, 0, 0)

// ---------------------------------------------------------------------------
// prep_k: weights -> bf16. W1b[640][256] = {wcur;wltrb}. W2b[256][640] with the
// torch permute+reshape channel shuffle folded into the K index.
// ---------------------------------------------------------------------------
__global__ __launch_bounds__(256) void prep_k(const float* __restrict__ wcur,
                                              const float* __restrict__ wltrb,
                                              const float* __restrict__ wout,
                                              ushort_t* __restrict__ W1b,
                                              ushort_t* __restrict__ W2b) {
    int id = blockIdx.x * 256 + threadIdx.x;
    if (id < CH1 * CIN) {
        const int ch = id / CIN;
        const float v = (ch < CB) ? wcur[id] : wltrb[id - CB * CIN];
        W1b[id] = f2bf(v);
        return;
    }
    id -= CH1 * CIN;
    if (id < O2 * K2) {
        const int o = id / K2, k = id % K2;
        const int korig = (k < 512) ? ((k & 127) * 4 + (k >> 7)) : k;
        W2b[id] = f2bf(wout[(size_t)o * K2 + korig]);
    }
}

// ---------------------------------------------------------------------------
// featT_k: feature fp32 [n][c][pix] -> bf16 channel-last [n][pix][256].
// LDS-transpose tiles of 128c x 64pix (grid y = c-half).
// ---------------------------------------------------------------------------
__global__ __launch_bounds__(256) void featT_k(const float* __restrict__ feat,
                                               ushort_t* __restrict__ featTb) {
    __shared__ float T[128][65];
    const int pix0 = blockIdx.x * 64;
    const int ch0  = blockIdx.y * 128;
    const int n    = blockIdx.z;
    const int tid  = threadIdx.x;
    {
        const int pl = tid & 63, cl0 = tid >> 6;
#pragma unroll
        for (int i = 0; i < 32; ++i) {
            const int cl = cl0 + i * 4;
            const int pix = pix0 + pl;
            T[cl][pl] = (pix < NPIX)
                ? feat[((size_t)n * CIN + ch0 + cl) * NPIX + pix] : 0.f;
        }
    }
    __syncthreads();
    const int cl = tid & 127, pl0 = tid >> 7;
#pragma unroll
    for (int j = 0; j < 32; ++j) {
        const int pp = pl0 + j * 2;
        const int pix = pix0 + pp;
        if (pix < NPIX)
            featTb[((size_t)n * NPIX + pix) * CIN + ch0 + cl] = f2bf(T[cl][pp]);
    }
}

// ---------------------------------------------------------------------------
// GEMM1 (MFMA bf16): raw[n][ch][pix] = sum_c W1[ch][c] * feat[n][c][pix]
// Block tile 64ch x 128pix, 4 waves (2 ch x 2 pix), per-wave 32ch x 64pix.
// B staged from featTb rows into LDS [128pix][40bf16] (pad 40 -> ds_read_b128
// and ds_write_b128 both hit the 8-dword/bank floor). A direct from L2.
// Epilogue: fused instance-norm sum/sumsq (16-lane butterfly + atomics),
// raw stored fp32 for norm_k.
// ---------------------------------------------------------------------------
__global__ __launch_bounds__(256) void gemm1_k(const ushort_t* __restrict__ featTb,
                                               const ushort_t* __restrict__ W1b,
                                               float* __restrict__ raw,
                                               float* __restrict__ st) {
    __shared__ ushort_t Bs[128][40];
    const int pix0 = blockIdx.x * 128;
    const int ch0  = blockIdx.y * 64;
    const int n    = blockIdx.z;
    const int tid  = threadIdx.x;
    const int lane = tid & 63, w = tid >> 6;
    const int wo = w & 1, wp = w >> 1;
    const int l15 = lane & 15, lg = lane >> 4;

    f32x4 acc[2][4];
#pragma unroll
    for (int am = 0; am < 2; ++am)
#pragma unroll
        for (int bn = 0; bn < 4; ++bn)
#pragma unroll
            for (int r = 0; r < 4; ++r) acc[am][bn][r] = 0.f;

    const int srow = tid >> 1, spart = tid & 1;
    const ushort_t* Bsrc = featTb + (size_t)n * NPIX * CIN;
    const ushort_t* A0 = W1b + (size_t)(ch0 + wo * 32 + l15) * CIN + lg * 8;
    const ushort_t* A1 = A0 + 16 * CIN;

    for (int ks = 0; ks < CIN / 32; ++ks) {
        const int k0 = ks * 32;
        {   // stage B: 128 rows x 32 k, 32B per thread
            const int pix = pix0 + srow;
            uint4 v0 = make_uint4(0, 0, 0, 0), v1 = v0;
            if (pix < NPIX) {
                const ushort_t* s = Bsrc + (size_t)pix * CIN + k0 + spart * 16;
                v0 = *(const uint4*)s;
                v1 = *(const uint4*)(s + 8);
            }
            *(uint4*)&Bs[srow][spart * 16]     = v0;
            *(uint4*)&Bs[srow][spart * 16 + 8] = v1;
        }
        __syncthreads();
        const bf16x8 a0 = *(const bf16x8*)(A0 + k0);
        const bf16x8 a1 = *(const bf16x8*)(A1 + k0);
#pragma unroll
        for (int bn = 0; bn < 4; ++bn) {
            const bf16x8 b = *(const bf16x8*)&Bs[wp * 64 + bn * 16 + l15][lg * 8];
            acc[0][bn] = MFMA16(a0, b, acc[0][bn]);
            acc[1][bn] = MFMA16(a1, b, acc[1][bn]);
        }
        __syncthreads();
    }

    // ---- fused instance-norm stats (pad pixels contribute exact 0) ----
#pragma unroll
    for (int am = 0; am < 2; ++am)
#pragma unroll
        for (int r = 0; r < 4; ++r) {
            float s = acc[am][0][r] + acc[am][1][r] + acc[am][2][r] + acc[am][3][r];
            float q = acc[am][0][r] * acc[am][0][r] + acc[am][1][r] * acc[am][1][r]
                    + acc[am][2][r] * acc[am][2][r] + acc[am][3][r] * acc[am][3][r];
#pragma unroll
            for (int o = 1; o < 16; o <<= 1) {
                s += __shfl_xor(s, o);
                q += __shfl_xor(q, o);
            }
            if (l15 == 0) {
                const int ch = ch0 + wo * 32 + am * 16 + lg * 4 + r;
                atomicAdd(&st[(size_t)(n * CH1 + ch) * 2],     s);
                atomicAdd(&st[(size_t)(n * CH1 + ch) * 2 + 1], q);
            }
        }

    // store raw fp32
#pragma unroll
    for (int am = 0; am < 2; ++am)
#pragma unroll
        for (int bn = 0; bn < 4; ++bn) {
            const int pix = pix0 + wp * 64 + bn * 16 + l15;
            if (pix < NPIX) {
                const int chb = ch0 + wo * 32 + am * 16 + lg * 4;
                float* dst = raw + ((size_t)n * CH1 + chb) * NPIX + pix;
#pragma unroll
                for (int r = 0; r < 4; ++r) dst[(size_t)r * NPIX] = acc[am][bn][r];
            }
        }
}

// ---------------------------------------------------------------------------
// Normalize + relu + transpose to channel-last:
//   ch in [0,128)   -> CATb slot 4 (bf16)      [n][5][pix][128]
//   ch in [128,640) -> L[n][border][pix][128]  (fp32, for bilinear gather)
// ---------------------------------------------------------------------------
__global__ __launch_bounds__(256) void norm_k(const float* __restrict__ raw,
                                              const float* __restrict__ st,
                                              float* __restrict__ L,
                                              ushort_t* __restrict__ CATb) {
    __shared__ float T[128][65];
    const int pix0 = blockIdx.x * 64;
    const int chb  = blockIdx.y;             // 0..4
    const int n    = blockIdx.z;
    const int tid  = threadIdx.x;
    {
        const int pl = tid & 63, cl0 = tid >> 6;
#pragma unroll
        for (int i = 0; i < 32; ++i) {
            const int cl = cl0 + i * 4;
            const int gidx = n * CH1 + chb * 128 + cl;
            const float sum = st[(size_t)gidx * 2];
            const float sq  = st[(size_t)gidx * 2 + 1];
            const float m = sum * (1.0f / (float)NPIX);
            const float var = fmaxf(sq * (1.0f / (float)NPIX) - m * m, 0.f);
            const float r = 1.0f / sqrtf(var + 1e-5f);
            const int pix = pix0 + pl;
            float v = (pix < NPIX) ? raw[(size_t)gidx * NPIX + pix] : 0.f;
            v = (v - m) * r;
            T[cl][pl] = fmaxf(v, 0.f);
        }
    }
    __syncthreads();
    const int cl = tid & 127, pl0 = tid >> 7;
    if (chb == 0) {
        ushort_t* dst = CATb + ((size_t)(n * 5 + 4) * NPIX) * 128;
#pragma unroll
        for (int j = 0; j < 32; ++j) {
            const int pp = pl0 + j * 2;
            const int pix = pix0 + pp;
            if (pix < NPIX) dst[(size_t)pix * 128 + cl] = f2bf(T[cl][pp]);
        }
    } else {
        float* dst = L + ((size_t)(n * 4 + (chb - 1)) * NPIX) * 128;
#pragma unroll
        for (int j = 0; j < 32; ++j) {
            const int pp = pl0 + j * 2;
            const int pix = pix0 + pp;
            if (pix < NPIX) dst[(size_t)pix * 128 + cl] = T[cl][pp];
        }
    }
}

// ---------------------------------------------------------------------------
// coord_k: one thread per (n, m=4p+b, sample k) -> bilinear descriptor
// (packed tap offset + valid-masked weights). Bit-identical coord math.
// ---------------------------------------------------------------------------
__global__ __launch_bounds__(256) void coord_k(const float* __restrict__ boxes,
                                               int* __restrict__ OFFS,
                                               float4* __restrict__ WTS) {
    const int id = blockIdx.x * 256 + threadIdx.x;
    if (id >= NB * NM * NSAMP) return;
    const int k  = id % NSAMP;
    const int mm = id / NSAMP;              // n*NM + m
    const int m  = mm % NM;
    const int n  = mm / NM;
    const int p = m >> 2, b = m & 3;
    const float* bx = boxes + ((size_t)n * NPIX + p) * 4;
    const float x1 = bx[0], y1 = bx[1], x2 = bx[2], y2 = bx[3];
    const float bw = __fsub_rn(x2, x1), bh = __fsub_rn(y2, y1);
    const float t = __fdiv_rn((float)k, 10.0f);
    float x, y;
    if (b == 0)      { x = __fadd_rn(x1, __fmul_rn(t, bw)); y = y1; }
    else if (b == 1) { x = x1; y = __fadd_rn(y1, __fmul_rn(t, bh)); }
    else if (b == 2) { x = __fadd_rn(x1, __fmul_rn(t, bw)); y = y2; }
    else             { x = x2; y = __fadd_rn(y1, __fmul_rn(t, bh)); }
    const bool valid = (x >= -1.f) && (x <= (float)WW) && (y >= -1.f) && (y <= (float)HH);
    x = fmaxf(x, 0.f); y = fmaxf(y, 0.f);
    const float x0f = floorf(x), y0f = floorf(y);
    const bool cx = (x0f >= (float)(WW - 1));
    const bool cy = (y0f >= (float)(HH - 1));
    const int ix0 = cx ? (WW - 1) : (int)x0f;
    const int iy0 = cy ? (HH - 1) : (int)y0f;
    const int ix1 = min(ix0 + 1, WW - 1);
    const int iy1 = min(iy0 + 1, HH - 1);
    const float lx = cx ? 0.f : __fsub_rn(x, (float)ix0);
    const float ly = cy ? 0.f : __fsub_rn(y, (float)iy0);
    const float hx = 1.f - lx, hy = 1.f - ly;
    const float vf = valid ? 1.f : 0.f;
    const int dx = ix1 - ix0, dy = iy1 - iy0;
    OFFS[id] = (iy0 * WW + ix0) | (dx << 14) | (dy << 15);
    WTS[id]  = make_float4((hy * hx) * vf, (hy * lx) * vf,
                           (ly * hx) * vf, (ly * lx) * vf);
}

// ---------------------------------------------------------------------------
// Border gather: 256 thr = 2 (n,m) units x 128 channels. fp32 gather from L,
// bf16 write to CATb slots 0..3 at m = 4*p + b.
// ---------------------------------------------------------------------------
__global__ __launch_bounds__(256) void border_k(const int* __restrict__ OFFS,
                                                const float4* __restrict__ WTS,
                                                const float* __restrict__ L,
                                                ushort_t* __restrict__ CATb) {
    const int half = threadIdx.x >> 7;
    const int c    = threadIdx.x & 127;
    const int mm   = blockIdx.x * 2 + half;       // n*NM + m
    const int m = mm % NM, n = mm / NM;
    const int b = m & 3;
    const float* Lb = L + ((size_t)(n * 4 + b) * NPIX) * 128 + c;
    const int base = mm * NSAMP;
    float acc = -INFINITY;
#pragma unroll
    for (int k = 0; k < NSAMP; ++k) {
        const int    v = OFFS[base + k];
        const float4 wt = WTS[base + k];
        const int off = v & 0x3FFF;
        const int dxo = ((v >> 14) & 1) * 128;
        const int dyo = ((v >> 15) & 1) * (WW * 128);
        const float* p = Lb + (size_t)off * 128;
        const float g00 = p[0];
        const float g01 = p[dxo];
        const float g10 = p[dyo];
        const float g11 = p[dyo + dxo];
        const float val = wt.x * g00 + wt.y * g01 + wt.z * g10 + wt.w * g11;
        acc = fmaxf(acc, val);
    }
    CATb[((size_t)n * 5 * NPIX + m) * 128 + c] = f2bf(acc);
}

// ---------------------------------------------------------------------------
// GEMM2 (MFMA bf16): out[n][o][pix] = relu(bout[o] + sum_k W2b[o][k]*CATb[..])
// Block tile 64o x 128pix, K=640, same staging structure as gemm1.
// ---------------------------------------------------------------------------
__global__ __launch_bounds__(256) void gemm2_k(const ushort_t* __restrict__ W2b,
                                               const ushort_t* __restrict__ CATb,
                                               const float* __restrict__ bout,
                                               float* __restrict__ out) {
    __shared__ ushort_t Bs[128][40];
    const int pix0 = blockIdx.x * 128;
    const int o0   = blockIdx.y * 64;
    const int n    = blockIdx.z;
    const int tid  = threadIdx.x;
    const int lane = tid & 63, w = tid >> 6;
    const int wo = w & 1, wp = w >> 1;
    const int l15 = lane & 15, lg = lane >> 4;

    f32x4 acc[2][4];
#pragma unroll
    for (int am = 0; am < 2; ++am)
#pragma unroll
        for (int bn = 0; bn < 4; ++bn)
#pragma unroll
            for (int r = 0; r < 4; ++r) acc[am][bn][r] = 0.f;

    const int srow = tid >> 1, spart = tid & 1;
    const ushort_t* CATn = CATb + (size_t)n * 5 * NPIX * 128;
    const ushort_t* A0 = W2b + (size_t)(o0 + wo * 32 + l15) * K2 + lg * 8;
    const ushort_t* A1 = A0 + 16 * K2;

    for (int ks = 0; ks < K2 / 32; ++ks) {
        const int k0 = ks * 32;
        const int slot = k0 >> 7, c0 = k0 & 127;
        {   // stage B: CATb rows (channel-last) 32-k slice
            const int pix = pix0 + srow;
            uint4 v0 = make_uint4(0, 0, 0, 0), v1 = v0;
            if (pix < NPIX) {
                const ushort_t* s = CATn + ((size_t)slot * NPIX + pix) * 128 + c0 + spart * 16;
                v0 = *(const uint4*)s;
                v1 = *(const uint4*)(s + 8);
            }
            *(uint4*)&Bs[srow][spart * 16]     = v0;
            *(uint4*)&Bs[srow][spart * 16 + 8] = v1;
        }
        __syncthreads();
        const bf16x8 a0 = *(const bf16x8*)(A0 + k0);
        const bf16x8 a1 = *(const bf16x8*)(A1 + k0);
#pragma unroll
        for (int bn = 0; bn < 4; ++bn) {
            const bf16x8 b = *(const bf16x8*)&Bs[wp * 64 + bn * 16 + l15][lg * 8];
            acc[0][bn] = MFMA16(a0, b, acc[0][bn]);
            acc[1][bn] = MFMA16(a1, b, acc[1][bn]);
        }
        __syncthreads();
    }

    // epilogue: bias + relu + store
    const int obase = o0 + wo * 32 + lg * 4;
#pragma unroll
    for (int am = 0; am < 2; ++am) {
        const float4 bi = *(const float4*)&bout[obase + am * 16];
#pragma unroll
        for (int bn = 0; bn < 4; ++bn) {
            const int pix = pix0 + wp * 64 + bn * 16 + l15;
            if (pix < NPIX) {
                float* dst = out + ((size_t)n * O2 + obase + am * 16) * NPIX + pix;
                dst[0 * (size_t)NPIX] = fmaxf(acc[am][bn][0] + bi.x, 0.f);
                dst[1 * (size_t)NPIX] = fmaxf(acc[am][bn][1] + bi.y, 0.f);
                dst[2 * (size_t)NPIX] = fmaxf(acc[am][bn][2] + bi.z, 0.f);
                dst[3 * (size_t)NPIX] = fmaxf(acc[am][bn][3] + bi.w, 0.f);
            }
        }
    }
}

// ---------------------------------------------------------------------------
extern "C" void kernel_launch(void* const* d_in, const int* in_sizes, int n_in,
                              void* d_out, int out_size, void* d_ws, size_t ws_size,
                              hipStream_t stream) {
    const float* feature = (const float*)d_in[0];   // [2,256,100,100]
    const float* boxes   = (const float*)d_in[1];   // [2,10000,4]
    // d_in[2] = wh (unused by the reference)
    const float* w_cur   = (const float*)d_in[3];   // [128,256]
    // d_in[4] = b_cur  (cancelled by instance norm)
    const float* w_ltrb  = (const float*)d_in[5];   // [512,256]
    // d_in[6] = b_ltrb (cancelled by instance norm)
    const float* w_out   = (const float*)d_in[7];   // [256,640]
    const float* b_out   = (const float*)d_in[8];   // [256]
    float* out = (float*)d_out;

    float* ws  = (float*)d_ws;
    float* raw = ws;                                   // 12,800,000 f (51.2MB)
    float* L   = raw + (size_t)NB * CH1 * NPIX;        // 10,240,000 f (41.0MB)
    float* st  = L + (size_t)NB * 4 * NPIX * 128;      // 2,560 f
    ushort_t* featTb = (ushort_t*)(st + NB * CH1 * 2); // 5,120,000 u16 (10.2MB)
    ushort_t* CATb   = featTb + (size_t)NB * NPIX * CIN;       // 12,800,000 u16 (25.6MB)
    ushort_t* W1b    = CATb + (size_t)NB * 5 * NPIX * 128;     // 163,840 u16
    ushort_t* W2b    = W1b + CH1 * CIN;                        // 163,840 u16

    // Sample descriptors alias raw (dead after norm_k; coord runs after norm).
    int*    OFFS = (int*)raw;
    float4* WTS  = (float4*)(raw + (1 << 20));

    hipMemsetAsync(st, 0, (size_t)NB * CH1 * 2 * sizeof(float), stream);
    prep_k<<<(CH1 * CIN + O2 * K2 + 255) / 256, 256, 0, stream>>>(w_cur, w_ltrb, w_out, W1b, W2b);
    featT_k<<<dim3((NPIX + 63) / 64, 2, NB), 256, 0, stream>>>(feature, featTb);
    gemm1_k<<<dim3((NPIX + 127) / 128, CH1 / 64, NB), 256, 0, stream>>>(featTb, W1b, raw, st);
    norm_k<<<dim3((NPIX + 63) / 64, 5, NB), 256, 0, stream>>>(raw, st, L, CATb);
    coord_k<<<(NB * NM * NSAMP + 255) / 256, 256, 0, stream>>>(boxes, OFFS, WTS);
    border_k<<<NB * NM / 2, 256, 0, stream>>>(OFFS, WTS, L, CATb);
    gemm2_k<<<dim3((NPIX + 127) / 128, O2 / 64, NB), 256, 0, stream>>>(W2b, CATb, b_out, out);
}

// Round 6
// 335.494 us; speedup vs baseline: 1.8848x; 1.1580x over previous
//
#include <hip/hip_runtime.h>
#include <hip/hip_bf16.h>
#include <math.h>

// Problem constants
#define NB    2
#define CIN   256
#define CB    128
#define HH    100
#define WW    100
#define NPIX  10000       // H*W
#define CH1   640         // 128 (cur) + 512 (ltrb)
#define K2    640         // final GEMM K
#define O2    256         // final GEMM M (output channels)
#define NM    40000       // 4 * NPIX  (flattened (box,border) units per n)
#define NSAMP 11          // POOL+1 samples per border

typedef __attribute__((ext_vector_type(8))) short bf16x8;   // 8 bf16 = 4 VGPR
typedef __attribute__((ext_vector_type(4))) float f32x4;    // MFMA accumulator
typedef unsigned short ushort_t;

__device__ __forceinline__ unsigned short f2bf(float f) {   // RNE f32->bf16
    unsigned u = __float_as_uint(f);
    u += 0x7FFF + ((u >> 16) & 1);
    return (unsigned short)(u >> 16);
}

#define MFMA16(a, b, c) __builtin_amdgcn_mfma_f32_16x16x32_bf16((a), (b), (c), 0, 0, 0)

// ---------------------------------------------------------------------------
// prep_k: weights -> bf16. W1b[640][256] = {wcur;wltrb}. W2b[256][640] with the
// torch permute+reshape channel shuffle folded into the K index.
// ---------------------------------------------------------------------------
__global__ __launch_bounds__(256) void prep_k(const float* __restrict__ wcur,
                                              const float* __restrict__ wltrb,
                                              const float* __restrict__ wout,
                                              ushort_t* __restrict__ W1b,
                                              ushort_t* __restrict__ W2b) {
    int id = blockIdx.x * 256 + threadIdx.x;
    if (id < CH1 * CIN) {
        const int ch = id / CIN;
        const float v = (ch < CB) ? wcur[id] : wltrb[id - CB * CIN];
        W1b[id] = f2bf(v);
        return;
    }
    id -= CH1 * CIN;
    if (id < O2 * K2) {
        const int o = id / K2, k = id % K2;
        const int korig = (k < 512) ? ((k & 127) * 4 + (k >> 7)) : k;
        W2b[id] = f2bf(wout[(size_t)o * K2 + korig]);
    }
}

// ---------------------------------------------------------------------------
// featT_k: feature fp32 [n][c][pix] -> bf16 channel-last [n][pix][256].
// LDS-transpose tiles of 128c x 64pix (grid y = c-half).
// ---------------------------------------------------------------------------
__global__ __launch_bounds__(256) void featT_k(const float* __restrict__ feat,
                                               ushort_t* __restrict__ featTb) {
    __shared__ float T[128][65];
    const int pix0 = blockIdx.x * 64;
    const int ch0  = blockIdx.y * 128;
    const int n    = blockIdx.z;
    const int tid  = threadIdx.x;
    {
        const int pl = tid & 63, cl0 = tid >> 6;
#pragma unroll
        for (int i = 0; i < 32; ++i) {
            const int cl = cl0 + i * 4;
            const int pix = pix0 + pl;
            T[cl][pl] = (pix < NPIX)
                ? feat[((size_t)n * CIN + ch0 + cl) * NPIX + pix] : 0.f;
        }
    }
    __syncthreads();
    const int cl = tid & 127, pl0 = tid >> 7;
#pragma unroll
    for (int j = 0; j < 32; ++j) {
        const int pp = pl0 + j * 2;
        const int pix = pix0 + pp;
        if (pix < NPIX)
            featTb[((size_t)n * NPIX + pix) * CIN + ch0 + cl] = f2bf(T[cl][pp]);
    }
}

// ---------------------------------------------------------------------------
// GEMM1 (MFMA bf16): raw[n][ch][pix] = sum_c W1[ch][c] * feat[n][c][pix]
// Block tile 64ch x 128pix, 4 waves (2 ch x 2 pix), per-wave 32ch x 64pix.
// Epilogue: fused instance-norm sum/sumsq; raw stored fp32 for norm_k.
// ---------------------------------------------------------------------------
__global__ __launch_bounds__(256) void gemm1_k(const ushort_t* __restrict__ featTb,
                                               const ushort_t* __restrict__ W1b,
                                               float* __restrict__ raw,
                                               float* __restrict__ st) {
    __shared__ ushort_t Bs[128][40];
    const int pix0 = blockIdx.x * 128;
    const int ch0  = blockIdx.y * 64;
    const int n    = blockIdx.z;
    const int tid  = threadIdx.x;
    const int lane = tid & 63, w = tid >> 6;
    const int wo = w & 1, wp = w >> 1;
    const int l15 = lane & 15, lg = lane >> 4;

    f32x4 acc[2][4];
#pragma unroll
    for (int am = 0; am < 2; ++am)
#pragma unroll
        for (int bn = 0; bn < 4; ++bn)
#pragma unroll
            for (int r = 0; r < 4; ++r) acc[am][bn][r] = 0.f;

    const int srow = tid >> 1, spart = tid & 1;
    const ushort_t* Bsrc = featTb + (size_t)n * NPIX * CIN;
    const ushort_t* A0 = W1b + (size_t)(ch0 + wo * 32 + l15) * CIN + lg * 8;
    const ushort_t* A1 = A0 + 16 * CIN;

    for (int ks = 0; ks < CIN / 32; ++ks) {
        const int k0 = ks * 32;
        {   // stage B: 128 rows x 32 k, 32B per thread
            const int pix = pix0 + srow;
            uint4 v0 = make_uint4(0, 0, 0, 0), v1 = v0;
            if (pix < NPIX) {
                const ushort_t* s = Bsrc + (size_t)pix * CIN + k0 + spart * 16;
                v0 = *(const uint4*)s;
                v1 = *(const uint4*)(s + 8);
            }
            *(uint4*)&Bs[srow][spart * 16]     = v0;
            *(uint4*)&Bs[srow][spart * 16 + 8] = v1;
        }
        __syncthreads();
        const bf16x8 a0 = *(const bf16x8*)(A0 + k0);
        const bf16x8 a1 = *(const bf16x8*)(A1 + k0);
#pragma unroll
        for (int bn = 0; bn < 4; ++bn) {
            const bf16x8 b = *(const bf16x8*)&Bs[wp * 64 + bn * 16 + l15][lg * 8];
            acc[0][bn] = MFMA16(a0, b, acc[0][bn]);
            acc[1][bn] = MFMA16(a1, b, acc[1][bn]);
        }
        __syncthreads();
    }

    // ---- fused instance-norm stats (pad pixels contribute exact 0) ----
#pragma unroll
    for (int am = 0; am < 2; ++am)
#pragma unroll
        for (int r = 0; r < 4; ++r) {
            float s = acc[am][0][r] + acc[am][1][r] + acc[am][2][r] + acc[am][3][r];
            float q = acc[am][0][r] * acc[am][0][r] + acc[am][1][r] * acc[am][1][r]
                    + acc[am][2][r] * acc[am][2][r] + acc[am][3][r] * acc[am][3][r];
#pragma unroll
            for (int o = 1; o < 16; o <<= 1) {
                s += __shfl_xor(s, o);
                q += __shfl_xor(q, o);
            }
            if (l15 == 0) {
                const int ch = ch0 + wo * 32 + am * 16 + lg * 4 + r;
                atomicAdd(&st[(size_t)(n * CH1 + ch) * 2],     s);
                atomicAdd(&st[(size_t)(n * CH1 + ch) * 2 + 1], q);
            }
        }

    // store raw fp32
#pragma unroll
    for (int am = 0; am < 2; ++am)
#pragma unroll
        for (int bn = 0; bn < 4; ++bn) {
            const int pix = pix0 + wp * 64 + bn * 16 + l15;
            if (pix < NPIX) {
                const int chb = ch0 + wo * 32 + am * 16 + lg * 4;
                float* dst = raw + ((size_t)n * CH1 + chb) * NPIX + pix;
#pragma unroll
                for (int r = 0; r < 4; ++r) dst[(size_t)r * NPIX] = acc[am][bn][r];
            }
        }
}

// ---------------------------------------------------------------------------
// Normalize + relu + transpose to channel-last:
//   ch in [0,128)   -> CATb slot 4 (bf16)      [n][5][pix][128]
//   ch in [128,640) -> L[n][border][pix][128]  (fp32, for bilinear gather)
// ---------------------------------------------------------------------------
__global__ __launch_bounds__(256) void norm_k(const float* __restrict__ raw,
                                              const float* __restrict__ st,
                                              float* __restrict__ L,
                                              ushort_t* __restrict__ CATb) {
    __shared__ float T[128][65];
    const int pix0 = blockIdx.x * 64;
    const int chb  = blockIdx.y;             // 0..4
    const int n    = blockIdx.z;
    const int tid  = threadIdx.x;
    {
        const int pl = tid & 63, cl0 = tid >> 6;
#pragma unroll
        for (int i = 0; i < 32; ++i) {
            const int cl = cl0 + i * 4;
            const int gidx = n * CH1 + chb * 128 + cl;
            const float sum = st[(size_t)gidx * 2];
            const float sq  = st[(size_t)gidx * 2 + 1];
            const float m = sum * (1.0f / (float)NPIX);
            const float var = fmaxf(sq * (1.0f / (float)NPIX) - m * m, 0.f);
            const float r = 1.0f / sqrtf(var + 1e-5f);
            const int pix = pix0 + pl;
            float v = (pix < NPIX) ? raw[(size_t)gidx * NPIX + pix] : 0.f;
            v = (v - m) * r;
            T[cl][pl] = fmaxf(v, 0.f);
        }
    }
    __syncthreads();
    const int cl = tid & 127, pl0 = tid >> 7;
    if (chb == 0) {
        ushort_t* dst = CATb + ((size_t)(n * 5 + 4) * NPIX) * 128;
#pragma unroll
        for (int j = 0; j < 32; ++j) {
            const int pp = pl0 + j * 2;
            const int pix = pix0 + pp;
            if (pix < NPIX) dst[(size_t)pix * 128 + cl] = f2bf(T[cl][pp]);
        }
    } else {
        float* dst = L + ((size_t)(n * 4 + (chb - 1)) * NPIX) * 128;
#pragma unroll
        for (int j = 0; j < 32; ++j) {
            const int pp = pl0 + j * 2;
            const int pix = pix0 + pp;
            if (pix < NPIX) dst[(size_t)pix * 128 + cl] = T[cl][pp];
        }
    }
}

// ---------------------------------------------------------------------------
// coord_k: one thread per (n, m=4p+b, sample k) -> bilinear descriptor
// (packed tap offset + valid-masked weights). Bit-identical coord math.
// Descriptors written SLICE-MAJOR: did = ((n*4+b)*NPIX + p)*NSAMP + k, so
// border_k's per-XCD slice streams contiguously.
// ---------------------------------------------------------------------------
__global__ __launch_bounds__(256) void coord_k(const float* __restrict__ boxes,
                                               int* __restrict__ OFFS,
                                               float4* __restrict__ WTS) {
    const int id = blockIdx.x * 256 + threadIdx.x;
    if (id >= NB * NM * NSAMP) return;
    const int k  = id % NSAMP;
    const int mm = id / NSAMP;              // n*NM + m
    const int m  = mm % NM;
    const int n  = mm / NM;
    const int p = m >> 2, b = m & 3;
    const float* bx = boxes + ((size_t)n * NPIX + p) * 4;
    const float x1 = bx[0], y1 = bx[1], x2 = bx[2], y2 = bx[3];
    const float bw = __fsub_rn(x2, x1), bh = __fsub_rn(y2, y1);
    const float t = __fdiv_rn((float)k, 10.0f);
    float x, y;
    if (b == 0)      { x = __fadd_rn(x1, __fmul_rn(t, bw)); y = y1; }
    else if (b == 1) { x = x1; y = __fadd_rn(y1, __fmul_rn(t, bh)); }
    else if (b == 2) { x = __fadd_rn(x1, __fmul_rn(t, bw)); y = y2; }
    else             { x = x2; y = __fadd_rn(y1, __fmul_rn(t, bh)); }
    const bool valid = (x >= -1.f) && (x <= (float)WW) && (y >= -1.f) && (y <= (float)HH);
    x = fmaxf(x, 0.f); y = fmaxf(y, 0.f);
    const float x0f = floorf(x), y0f = floorf(y);
    const bool cx = (x0f >= (float)(WW - 1));
    const bool cy = (y0f >= (float)(HH - 1));
    const int ix0 = cx ? (WW - 1) : (int)x0f;
    const int iy0 = cy ? (HH - 1) : (int)y0f;
    const int ix1 = min(ix0 + 1, WW - 1);
    const int iy1 = min(iy0 + 1, HH - 1);
    const float lx = cx ? 0.f : __fsub_rn(x, (float)ix0);
    const float ly = cy ? 0.f : __fsub_rn(y, (float)iy0);
    const float hx = 1.f - lx, hy = 1.f - ly;
    const float vf = valid ? 1.f : 0.f;
    const int dx = ix1 - ix0, dy = iy1 - iy0;
    const int did = (((n * 4 + b) * NPIX) + p) * NSAMP + k;   // slice-major
    OFFS[did] = (iy0 * WW + ix0) | (dx << 14) | (dy << 15);
    WTS[did]  = make_float4((hy * hx) * vf, (hy * lx) * vf,
                            (ly * hx) * vf, (ly * lx) * vf);
}

// ---------------------------------------------------------------------------
// Border gather, XCD-affine + float4-vectorized:
//   slice s = blockIdx.x & 7  ->  (n = s>>2, border b = s&3)   [8 slices = 8 XCDs;
//   dispatch round-robins blockIdx%8 across XCDs -> each XCD's L2 holds one
//   5.1MB L-slice instead of all 41MB]
//   8 units (pixels) per 256-thr block, 32 lanes/unit, lane = 4 channels.
// Per-channel arithmetic identical to previous round (bit-identical output).
// ---------------------------------------------------------------------------
__global__ __launch_bounds__(256) void border_k(const int* __restrict__ OFFS,
                                                const float4* __restrict__ WTS,
                                                const float* __restrict__ L,
                                                ushort_t* __restrict__ CATb) {
    const int s = blockIdx.x & 7;            // slice -> XCD affinity
    const int n = s >> 2, b = s & 3;
    const int u = threadIdx.x >> 5;          // unit in block: 0..7
    const int c4 = (threadIdx.x & 31) * 4;   // channel base
    const int p = (blockIdx.x >> 3) * 8 + u; // pixel (box) index
    const float* Lb = L + ((size_t)(n * 4 + b) * NPIX) * 128 + c4;
    const int base = (((n * 4 + b) * NPIX) + p) * NSAMP;
    float ax = -INFINITY, ay = -INFINITY, az = -INFINITY, aw = -INFINITY;
#pragma unroll
    for (int k = 0; k < NSAMP; ++k) {
        const int    v  = OFFS[base + k];
        const float4 wt = WTS[base + k];
        const int off = v & 0x3FFF;
        const int dxo = ((v >> 14) & 1) * 128;
        const int dyo = ((v >> 15) & 1) * (WW * 128);
        const float* pb = Lb + (size_t)off * 128;
        const float4 g00 = *(const float4*)(pb);
        const float4 g01 = *(const float4*)(pb + dxo);
        const float4 g10 = *(const float4*)(pb + dyo);
        const float4 g11 = *(const float4*)(pb + dyo + dxo);
        const float vx = wt.x * g00.x + wt.y * g01.x + wt.z * g10.x + wt.w * g11.x;
        const float vy = wt.x * g00.y + wt.y * g01.y + wt.z * g10.y + wt.w * g11.y;
        const float vz = wt.x * g00.z + wt.y * g01.z + wt.z * g10.z + wt.w * g11.z;
        const float vw = wt.x * g00.w + wt.y * g01.w + wt.z * g10.w + wt.w * g11.w;
        ax = fmaxf(ax, vx); ay = fmaxf(ay, vy);
        az = fmaxf(az, vz); aw = fmaxf(aw, vw);
    }
    const int m = p * 4 + b;
    ushort_t* dst = CATb + ((size_t)n * 5 * NPIX + m) * 128 + c4;
    dst[0] = f2bf(ax); dst[1] = f2bf(ay); dst[2] = f2bf(az); dst[3] = f2bf(aw);
}

// ---------------------------------------------------------------------------
// GEMM2 (MFMA bf16): out[n][o][pix] = relu(bout[o] + sum_k W2b[o][k]*CATb[..])
// Block tile 64o x 128pix, K=640, same staging structure as gemm1.
// ---------------------------------------------------------------------------
__global__ __launch_bounds__(256) void gemm2_k(const ushort_t* __restrict__ W2b,
                                               const ushort_t* __restrict__ CATb,
                                               const float* __restrict__ bout,
                                               float* __restrict__ out) {
    __shared__ ushort_t Bs[128][40];
    const int pix0 = blockIdx.x * 128;
    const int o0   = blockIdx.y * 64;
    const int n    = blockIdx.z;
    const int tid  = threadIdx.x;
    const int lane = tid & 63, w = tid >> 6;
    const int wo = w & 1, wp = w >> 1;
    const int l15 = lane & 15, lg = lane >> 4;

    f32x4 acc[2][4];
#pragma unroll
    for (int am = 0; am < 2; ++am)
#pragma unroll
        for (int bn = 0; bn < 4; ++bn)
#pragma unroll
            for (int r = 0; r < 4; ++r) acc[am][bn][r] = 0.f;

    const int srow = tid >> 1, spart = tid & 1;
    const ushort_t* CATn = CATb + (size_t)n * 5 * NPIX * 128;
    const ushort_t* A0 = W2b + (size_t)(o0 + wo * 32 + l15) * K2 + lg * 8;
    const ushort_t* A1 = A0 + 16 * K2;

    for (int ks = 0; ks < K2 / 32; ++ks) {
        const int k0 = ks * 32;
        const int slot = k0 >> 7, c0 = k0 & 127;
        {   // stage B: CATb rows (channel-last) 32-k slice
            const int pix = pix0 + srow;
            uint4 v0 = make_uint4(0, 0, 0, 0), v1 = v0;
            if (pix < NPIX) {
                const ushort_t* s = CATn + ((size_t)slot * NPIX + pix) * 128 + c0 + spart * 16;
                v0 = *(const uint4*)s;
                v1 = *(const uint4*)(s + 8);
            }
            *(uint4*)&Bs[srow][spart * 16]     = v0;
            *(uint4*)&Bs[srow][spart * 16 + 8] = v1;
        }
        __syncthreads();
        const bf16x8 a0 = *(const bf16x8*)(A0 + k0);
        const bf16x8 a1 = *(const bf16x8*)(A1 + k0);
#pragma unroll
        for (int bn = 0; bn < 4; ++bn) {
            const bf16x8 b = *(const bf16x8*)&Bs[wp * 64 + bn * 16 + l15][lg * 8];
            acc[0][bn] = MFMA16(a0, b, acc[0][bn]);
            acc[1][bn] = MFMA16(a1, b, acc[1][bn]);
        }
        __syncthreads();
    }

    // epilogue: bias + relu + store
    const int obase = o0 + wo * 32 + lg * 4;
#pragma unroll
    for (int am = 0; am < 2; ++am) {
        const float4 bi = *(const float4*)&bout[obase + am * 16];
#pragma unroll
        for (int bn = 0; bn < 4; ++bn) {
            const int pix = pix0 + wp * 64 + bn * 16 + l15;
            if (pix < NPIX) {
                float* dst = out + ((size_t)n * O2 + obase + am * 16) * NPIX + pix;
                dst[0 * (size_t)NPIX] = fmaxf(acc[am][bn][0] + bi.x, 0.f);
                dst[1 * (size_t)NPIX] = fmaxf(acc[am][bn][1] + bi.y, 0.f);
                dst[2 * (size_t)NPIX] = fmaxf(acc[am][bn][2] + bi.z, 0.f);
                dst[3 * (size_t)NPIX] = fmaxf(acc[am][bn][3] + bi.w, 0.f);
            }
        }
    }
}

// ---------------------------------------------------------------------------
extern "C" void kernel_launch(void* const* d_in, const int* in_sizes, int n_in,
                              void* d_out, int out_size, void* d_ws, size_t ws_size,
                              hipStream_t stream) {
    const float* feature = (const float*)d_in[0];   // [2,256,100,100]
    const float* boxes   = (const float*)d_in[1];   // [2,10000,4]
    // d_in[2] = wh (unused by the reference)
    const float* w_cur   = (const float*)d_in[3];   // [128,256]
    // d_in[4] = b_cur  (cancelled by instance norm)
    const float* w_ltrb  = (const float*)d_in[5];   // [512,256]
    // d_in[6] = b_ltrb (cancelled by instance norm)
    const float* w_out   = (const float*)d_in[7];   // [256,640]
    const float* b_out   = (const float*)d_in[8];   // [256]
    float* out = (float*)d_out;

    float* ws  = (float*)d_ws;
    float* raw = ws;                                   // 12,800,000 f (51.2MB)
    float* L   = raw + (size_t)NB * CH1 * NPIX;        // 10,240,000 f (41.0MB)
    float* st  = L + (size_t)NB * 4 * NPIX * 128;      // 2,560 f
    ushort_t* featTb = (ushort_t*)(st + NB * CH1 * 2); // 5,120,000 u16 (10.2MB)
    ushort_t* CATb   = featTb + (size_t)NB * NPIX * CIN;       // 12,800,000 u16 (25.6MB)
    ushort_t* W1b    = CATb + (size_t)NB * 5 * NPIX * 128;     // 163,840 u16
    ushort_t* W2b    = W1b + CH1 * CIN;                        // 163,840 u16

    // Sample descriptors alias raw (dead after norm_k; coord runs after norm).
    int*    OFFS = (int*)raw;
    float4* WTS  = (float4*)(raw + (1 << 20));

    hipMemsetAsync(st, 0, (size_t)NB * CH1 * 2 * sizeof(float), stream);
    prep_k<<<(CH1 * CIN + O2 * K2 + 255) / 256, 256, 0, stream>>>(w_cur, w_ltrb, w_out, W1b, W2b);
    featT_k<<<dim3((NPIX + 63) / 64, 2, NB), 256, 0, stream>>>(feature, featTb);
    gemm1_k<<<dim3((NPIX + 127) / 128, CH1 / 64, NB), 256, 0, stream>>>(featTb, W1b, raw, st);
    norm_k<<<dim3((NPIX + 63) / 64, 5, NB), 256, 0, stream>>>(raw, st, L, CATb);
    coord_k<<<(NB * NM * NSAMP + 255) / 256, 256, 0, stream>>>(boxes, OFFS, WTS);
    border_k<<<NB * 4 * NPIX / 8, 256, 0, stream>>>(OFFS, WTS, L, CATb);
    gemm2_k<<<dim3((NPIX + 127) / 128, O2 / 64, NB), 256, 0, stream>>>(W2b, CATb, b_out, out);
}

// Round 7
// 247.225 us; speedup vs baseline: 2.5577x; 1.3570x over previous
//
#include <hip/hip_runtime.h>
#include <hip/hip_bf16.h>
#include <math.h>

// Problem constants
#define NB    2
#define CIN   256
#define CB    128
#define HH    100
#define WW    100
#define NPIX  10000       // H*W
#define CH1   640         // 128 (cur) + 512 (ltrb)
#define K2    640         // final GEMM K
#define O2    256         // final GEMM M (output channels)
#define NM    40000       // 4 * NPIX  (flattened (box,border) units per n)
#define NSAMP 11          // POOL+1 samples per border

typedef __attribute__((ext_vector_type(8))) short bf16x8;   // 8 bf16 = 4 VGPR
typedef __attribute__((ext_vector_type(4))) float f32x4;    // MFMA accumulator
typedef unsigned short ushort_t;

__device__ __forceinline__ unsigned short f2bf(float f) {   // RNE f32->bf16
    unsigned u = __float_as_uint(f);
    u += 0x7FFF + ((u >> 16) & 1);
    return (unsigned short)(u >> 16);
}
__device__ __forceinline__ float bf2f(ushort_t u) {
    return __uint_as_float(((unsigned)u) << 16);
}

#define MFMA16(a, b, c) __builtin_amdgcn_mfma_f32_16x16x32_bf16((a), (b), (c), 0, 0, 0)

// ---------------------------------------------------------------------------
// prep_k: weights -> bf16. W1b[640][256] = {wcur;wltrb}. W2b[256][640] with the
// torch permute+reshape channel shuffle folded into the K index.
// ---------------------------------------------------------------------------
__global__ __launch_bounds__(256) void prep_k(const float* __restrict__ wcur,
                                              const float* __restrict__ wltrb,
                                              const float* __restrict__ wout,
                                              ushort_t* __restrict__ W1b,
                                              ushort_t* __restrict__ W2b) {
    int id = blockIdx.x * 256 + threadIdx.x;
    if (id < CH1 * CIN) {
        const int ch = id / CIN;
        const float v = (ch < CB) ? wcur[id] : wltrb[id - CB * CIN];
        W1b[id] = f2bf(v);
        return;
    }
    id -= CH1 * CIN;
    if (id < O2 * K2) {
        const int o = id / K2, k = id % K2;
        const int korig = (k < 512) ? ((k & 127) * 4 + (k >> 7)) : k;
        W2b[id] = f2bf(wout[(size_t)o * K2 + korig]);
    }
}

// ---------------------------------------------------------------------------
// featT_k: feature fp32 [n][c][pix] -> bf16 channel-last [n][pix][256].
// ---------------------------------------------------------------------------
__global__ __launch_bounds__(256) void featT_k(const float* __restrict__ feat,
                                               ushort_t* __restrict__ featTb) {
    __shared__ float T[128][65];
    const int pix0 = blockIdx.x * 64;
    const int ch0  = blockIdx.y * 128;
    const int n    = blockIdx.z;
    const int tid  = threadIdx.x;
    {
        const int pl = tid & 63, cl0 = tid >> 6;
#pragma unroll
        for (int i = 0; i < 32; ++i) {
            const int cl = cl0 + i * 4;
            const int pix = pix0 + pl;
            T[cl][pl] = (pix < NPIX)
                ? feat[((size_t)n * CIN + ch0 + cl) * NPIX + pix] : 0.f;
        }
    }
    __syncthreads();
    const int cl = tid & 127, pl0 = tid >> 7;
#pragma unroll
    for (int j = 0; j < 32; ++j) {
        const int pp = pl0 + j * 2;
        const int pix = pix0 + pp;
        if (pix < NPIX)
            featTb[((size_t)n * NPIX + pix) * CIN + ch0 + cl] = f2bf(T[cl][pp]);
    }
}

// ---------------------------------------------------------------------------
// GEMM1T (MFMA bf16, swapped operands -> channel-LAST output):
//   rawT[n][pix][ch] = sum_c feat[n][pix][c] * W1[ch][c]    (bf16 store)
// Tile 128pix x 128ch, 4 waves (2pix x 2ch halves), per-wave 64x64 = 16 MFMA.
// A-frags (pix) from LDS-staged featTb rows; B-frags (ch) from L2 (W1b).
// Register-prefetch: next K-chunk's staging loads issued during current MFMA.
// Epilogue: fused instance-norm sum/sumsq (fp32 acc, pre-rounding) + atomics.
// ---------------------------------------------------------------------------
__global__ __launch_bounds__(256) void gemm1T_k(const ushort_t* __restrict__ featTb,
                                                const ushort_t* __restrict__ W1b,
                                                ushort_t* __restrict__ rawT,
                                                float* __restrict__ st) {
    __shared__ ushort_t Bs[128][40];
    const int pix0 = blockIdx.x * 128;
    const int ch0  = blockIdx.y * 128;
    const int n    = blockIdx.z;
    const int tid  = threadIdx.x;
    const int lane = tid & 63, wv = tid >> 6;
    const int wp = wv & 1, wc = wv >> 1;          // pix half / ch half
    const int l15 = lane & 15, lg = lane >> 4;

    f32x4 acc[4][4];                              // [am(pix)][bn(ch)]
#pragma unroll
    for (int am = 0; am < 4; ++am)
#pragma unroll
        for (int bn = 0; bn < 4; ++bn)
#pragma unroll
            for (int r = 0; r < 4; ++r) acc[am][bn][r] = 0.f;

    const int srow = tid >> 1, spart = tid & 1;
    const ushort_t* Bsrc  = featTb + (size_t)n * NPIX * CIN;
    const ushort_t* Wbase = W1b + (size_t)(ch0 + wc * 64 + l15) * CIN + lg * 8;

    uint4 pv0, pv1;
    {   // prologue: stage chunk 0 into regs
        const int pix = pix0 + srow;
        pv0 = make_uint4(0, 0, 0, 0); pv1 = pv0;
        if (pix < NPIX) {
            const ushort_t* s = Bsrc + (size_t)pix * CIN + spart * 16;
            pv0 = *(const uint4*)s;
            pv1 = *(const uint4*)(s + 8);
        }
    }
#pragma unroll
    for (int ks = 0; ks < CIN / 32; ++ks) {
        const int k0 = ks * 32;
        *(uint4*)&Bs[srow][spart * 16]     = pv0;
        *(uint4*)&Bs[srow][spart * 16 + 8] = pv1;
        __syncthreads();
        if (ks + 1 < CIN / 32) {   // prefetch next chunk (hidden under MFMA)
            const int pix = pix0 + srow;
            pv0 = make_uint4(0, 0, 0, 0); pv1 = pv0;
            if (pix < NPIX) {
                const ushort_t* s = Bsrc + (size_t)pix * CIN + (k0 + 32) + spart * 16;
                pv0 = *(const uint4*)s;
                pv1 = *(const uint4*)(s + 8);
            }
        }
        bf16x8 bfrag[4];
#pragma unroll
        for (int bn = 0; bn < 4; ++bn)
            bfrag[bn] = *(const bf16x8*)(Wbase + (size_t)bn * 16 * CIN + k0);
#pragma unroll
        for (int am = 0; am < 4; ++am) {
            const bf16x8 a = *(const bf16x8*)&Bs[wp * 64 + am * 16 + l15][lg * 8];
#pragma unroll
            for (int bn = 0; bn < 4; ++bn)
                acc[am][bn] = MFMA16(a, bfrag[bn], acc[am][bn]);
        }
        __syncthreads();
    }

    // ---- fused instance-norm stats (pad pixels staged as 0 -> contribute 0) ----
#pragma unroll
    for (int bn = 0; bn < 4; ++bn) {
        float s = 0.f, q = 0.f;
#pragma unroll
        for (int am = 0; am < 4; ++am)
#pragma unroll
            for (int r = 0; r < 4; ++r) { const float v = acc[am][bn][r]; s += v; q += v * v; }
        s += __shfl_xor(s, 16); q += __shfl_xor(q, 16);
        s += __shfl_xor(s, 32); q += __shfl_xor(q, 32);
        if (lg == 0) {
            const int ch = ch0 + wc * 64 + bn * 16 + l15;
            atomicAdd(&st[(size_t)(n * CH1 + ch) * 2],     s);
            atomicAdd(&st[(size_t)(n * CH1 + ch) * 2 + 1], q);
        }
    }

    // store rawT bf16 channel-last: pix = row (lg*4+r), ch = col (l15)
#pragma unroll
    for (int am = 0; am < 4; ++am)
#pragma unroll
        for (int r = 0; r < 4; ++r) {
            const int pix = pix0 + wp * 64 + am * 16 + lg * 4 + r;
            if (pix < NPIX) {
                ushort_t* dst = rawT + (size_t)(n * NPIX + pix) * CH1 + ch0 + wc * 64 + l15;
#pragma unroll
                for (int bn = 0; bn < 4; ++bn) dst[bn * 16] = f2bf(acc[am][bn][r]);
            }
        }
}

// ---------------------------------------------------------------------------
// stfin_k: finalize per-(n,ch) mean / rstd from fused sums (same math as the
// previous norm_k). MS[n*CH1+ch] = {m, 1/sqrt(var+eps)}.
// ---------------------------------------------------------------------------
__global__ __launch_bounds__(256) void stfin_k(const float* __restrict__ st,
                                               float2* __restrict__ MS) {
    const int ch = blockIdx.x * 256 + threadIdx.x;
    if (ch >= NB * CH1) return;
    const float sum = st[(size_t)ch * 2];
    const float sq  = st[(size_t)ch * 2 + 1];
    const float m   = sum * (1.0f / (float)NPIX);
    const float var = fmaxf(sq * (1.0f / (float)NPIX) - m * m, 0.f);
    MS[ch] = make_float2(m, 1.0f / sqrtf(var + 1e-5f));
}

// ---------------------------------------------------------------------------
// norm4_k: fm_short slot (ch 0..128): stream rawT, scale+relu, write CATb
// slot 4. Pure streaming, bf16x8 per thread, no LDS.
// ---------------------------------------------------------------------------
__global__ __launch_bounds__(256) void norm4_k(const ushort_t* __restrict__ rawT,
                                               const float2* __restrict__ MS,
                                               ushort_t* __restrict__ CATb) {
    const int id = blockIdx.x * 256 + threadIdx.x;   // (n*NPIX+pix)*16 + c8grp
    if (id >= NB * NPIX * 16) return;
    const int c8 = (id & 15) * 8;
    const int np = id >> 4;                          // n*NPIX + pix
    const int n = np / NPIX, pix = np % NPIX;
    const uint4 v = *(const uint4*)(rawT + (size_t)np * CH1 + c8);
    ushort_t tmp[8]; *(uint4*)tmp = v;
    ushort_t outv[8];
    const float2* msb = MS + n * CH1 + c8;
#pragma unroll
    for (int j = 0; j < 8; ++j) {
        const float2 ms = msb[j];
        const float x = (bf2f(tmp[j]) - ms.x) * ms.y;
        outv[j] = f2bf(fmaxf(x, 0.f));
    }
    *(uint4*)(CATb + ((size_t)(n * 5 + 4) * NPIX + pix) * 128 + c8) = *(uint4*)outv;
}

// ---------------------------------------------------------------------------
// coord_k: one thread per (n, m=4p+b, sample k) -> bilinear descriptor
// (packed tap offset + valid-masked weights). Bit-identical coord math.
// Slice-major layout for XCD-affine border gather.
// ---------------------------------------------------------------------------
__global__ __launch_bounds__(256) void coord_k(const float* __restrict__ boxes,
                                               int* __restrict__ OFFS,
                                               float4* __restrict__ WTS) {
    const int id = blockIdx.x * 256 + threadIdx.x;
    if (id >= NB * NM * NSAMP) return;
    const int k  = id % NSAMP;
    const int mm = id / NSAMP;              // n*NM + m
    const int m  = mm % NM;
    const int n  = mm / NM;
    const int p = m >> 2, b = m & 3;
    const float* bx = boxes + ((size_t)n * NPIX + p) * 4;
    const float x1 = bx[0], y1 = bx[1], x2 = bx[2], y2 = bx[3];
    const float bw = __fsub_rn(x2, x1), bh = __fsub_rn(y2, y1);
    const float t = __fdiv_rn((float)k, 10.0f);
    float x, y;
    if (b == 0)      { x = __fadd_rn(x1, __fmul_rn(t, bw)); y = y1; }
    else if (b == 1) { x = x1; y = __fadd_rn(y1, __fmul_rn(t, bh)); }
    else if (b == 2) { x = __fadd_rn(x1, __fmul_rn(t, bw)); y = y2; }
    else             { x = x2; y = __fadd_rn(y1, __fmul_rn(t, bh)); }
    const bool valid = (x >= -1.f) && (x <= (float)WW) && (y >= -1.f) && (y <= (float)HH);
    x = fmaxf(x, 0.f); y = fmaxf(y, 0.f);
    const float x0f = floorf(x), y0f = floorf(y);
    const bool cx = (x0f >= (float)(WW - 1));
    const bool cy = (y0f >= (float)(HH - 1));
    const int ix0 = cx ? (WW - 1) : (int)x0f;
    const int iy0 = cy ? (HH - 1) : (int)y0f;
    const int ix1 = min(ix0 + 1, WW - 1);
    const int iy1 = min(iy0 + 1, HH - 1);
    const float lx = cx ? 0.f : __fsub_rn(x, (float)ix0);
    const float ly = cy ? 0.f : __fsub_rn(y, (float)iy0);
    const float hx = 1.f - lx, hy = 1.f - ly;
    const float vf = valid ? 1.f : 0.f;
    const int dx = ix1 - ix0, dy = iy1 - iy0;
    const int did = (((n * 4 + b) * NPIX) + p) * NSAMP + k;   // slice-major
    OFFS[did] = (iy0 * WW + ix0) | (dx << 14) | (dy << 15);
    WTS[did]  = make_float4((hy * hx) * vf, (hy * lx) * vf,
                            (ly * hx) * vf, (ly * lx) * vf);
}

// ---------------------------------------------------------------------------
// borderN_k: gather directly from bf16 rawT with inline normalize+relu.
// relu((x-m)*r) = r * relu(x-m)  (r>0) -> r factored out of the tap loop.
// XCD-affine: slice s = blockIdx.x & 7 -> (n,b); per-XCD hot set = 2.56 MB
// (10000 pix x 128 ch x 2B) -> fits the 4 MB XCD L2.
// 8 units x 32 lanes (4 ch each) per 256-thr block.
// ---------------------------------------------------------------------------
__global__ __launch_bounds__(256) void borderN_k(const int* __restrict__ OFFS,
                                                 const float4* __restrict__ WTS,
                                                 const ushort_t* __restrict__ rawT,
                                                 const float2* __restrict__ MS,
                                                 ushort_t* __restrict__ CATb) {
    const int s = blockIdx.x & 7;            // slice -> XCD affinity
    const int n = s >> 2, b = s & 3;
    const int u = threadIdx.x >> 5;          // unit in block: 0..7
    const int c4 = (threadIdx.x & 31) * 4;   // channel base within border
    const int p = (blockIdx.x >> 3) * 8 + u; // pixel (box) index
    const int chb = CB + b * CB + c4;        // rawT column base
    const float4 q0 = *(const float4*)(MS + n * CH1 + chb);      // m0,r0,m1,r1
    const float4 q1 = *(const float4*)(MS + n * CH1 + chb + 2);  // m2,r2,m3,r3
    const ushort_t* base = rawT + (size_t)n * NPIX * CH1 + chb;
    const int dbase = (((n * 4 + b) * NPIX) + p) * NSAMP;
    float ax = -INFINITY, ay = -INFINITY, az = -INFINITY, aw = -INFINITY;
#pragma unroll
    for (int k = 0; k < NSAMP; ++k) {
        const int    v  = OFFS[dbase + k];
        const float4 wt = WTS[dbase + k];
        const int off = v & 0x3FFF;
        const int dxo = ((v >> 14) & 1) * CH1;
        const int dyo = ((v >> 15) & 1) * (WW * CH1);
        const ushort_t* t00 = base + (size_t)off * CH1;
        const ushort4 u00 = *(const ushort4*)(t00);
        const ushort4 u01 = *(const ushort4*)(t00 + dxo);
        const ushort4 u10 = *(const ushort4*)(t00 + dyo);
        const ushort4 u11 = *(const ushort4*)(t00 + dyo + dxo);
        // per-channel: sum_i w_i * relu(x_i - m), then * r
        float s0 = wt.x * fmaxf(bf2f(u00.x) - q0.x, 0.f);
        float s1 = wt.x * fmaxf(bf2f(u00.y) - q0.z, 0.f);
        float s2 = wt.x * fmaxf(bf2f(u00.z) - q1.x, 0.f);
        float s3 = wt.x * fmaxf(bf2f(u00.w) - q1.z, 0.f);
        s0 = fmaf(wt.y, fmaxf(bf2f(u01.x) - q0.x, 0.f), s0);
        s1 = fmaf(wt.y, fmaxf(bf2f(u01.y) - q0.z, 0.f), s1);
        s2 = fmaf(wt.y, fmaxf(bf2f(u01.z) - q1.x, 0.f), s2);
        s3 = fmaf(wt.y, fmaxf(bf2f(u01.w) - q1.z, 0.f), s3);
        s0 = fmaf(wt.z, fmaxf(bf2f(u10.x) - q0.x, 0.f), s0);
        s1 = fmaf(wt.z, fmaxf(bf2f(u10.y) - q0.z, 0.f), s1);
        s2 = fmaf(wt.z, fmaxf(bf2f(u10.z) - q1.x, 0.f), s2);
        s3 = fmaf(wt.z, fmaxf(bf2f(u10.w) - q1.z, 0.f), s3);
        s0 = fmaf(wt.w, fmaxf(bf2f(u11.x) - q0.x, 0.f), s0);
        s1 = fmaf(wt.w, fmaxf(bf2f(u11.y) - q0.z, 0.f), s1);
        s2 = fmaf(wt.w, fmaxf(bf2f(u11.z) - q1.x, 0.f), s2);
        s3 = fmaf(wt.w, fmaxf(bf2f(u11.w) - q1.z, 0.f), s3);
        ax = fmaxf(ax, q0.y * s0); ay = fmaxf(ay, q0.w * s1);
        az = fmaxf(az, q1.y * s2); aw = fmaxf(aw, q1.w * s3);
    }
    const int m = p * 4 + b;
    ushort_t* dst = CATb + ((size_t)n * 5 * NPIX + m) * 128 + c4;
    dst[0] = f2bf(ax); dst[1] = f2bf(ay); dst[2] = f2bf(az); dst[3] = f2bf(aw);
}

// ---------------------------------------------------------------------------
// GEMM2 (MFMA bf16 + reg-prefetch): out = relu(bout + W2b x CATb), fp32 out.
// Block tile 64o x 128pix, K=640 in 20 chunks of 32.
// ---------------------------------------------------------------------------
__global__ __launch_bounds__(256) void gemm2_k(const ushort_t* __restrict__ W2b,
                                               const ushort_t* __restrict__ CATb,
                                               const float* __restrict__ bout,
                                               float* __restrict__ out) {
    __shared__ ushort_t Bs[128][40];
    const int pix0 = blockIdx.x * 128;
    const int o0   = blockIdx.y * 64;
    const int n    = blockIdx.z;
    const int tid  = threadIdx.x;
    const int lane = tid & 63, wv = tid >> 6;
    const int wo = wv & 1, wp = wv >> 1;
    const int l15 = lane & 15, lg = lane >> 4;

    f32x4 acc[2][4];
#pragma unroll
    for (int am = 0; am < 2; ++am)
#pragma unroll
        for (int bn = 0; bn < 4; ++bn)
#pragma unroll
            for (int r = 0; r < 4; ++r) acc[am][bn][r] = 0.f;

    const int srow = tid >> 1, spart = tid & 1;
    const ushort_t* CATn = CATb + (size_t)n * 5 * NPIX * 128;
    const ushort_t* A0 = W2b + (size_t)(o0 + wo * 32 + l15) * K2 + lg * 8;
    const ushort_t* A1 = A0 + 16 * K2;

    uint4 pv0, pv1;
    {   // prologue: chunk 0 (slot 0, c0 0)
        const int pix = pix0 + srow;
        pv0 = make_uint4(0, 0, 0, 0); pv1 = pv0;
        if (pix < NPIX) {
            const ushort_t* s = CATn + (size_t)pix * 128 + spart * 16;
            pv0 = *(const uint4*)s;
            pv1 = *(const uint4*)(s + 8);
        }
    }
#pragma unroll
    for (int ks = 0; ks < K2 / 32; ++ks) {
        const int k0 = ks * 32;
        *(uint4*)&Bs[srow][spart * 16]     = pv0;
        *(uint4*)&Bs[srow][spart * 16 + 8] = pv1;
        __syncthreads();
        if (ks + 1 < K2 / 32) {   // prefetch next chunk
            const int k0n = k0 + 32;
            const int slot = k0n >> 7, c0 = k0n & 127;
            const int pix = pix0 + srow;
            pv0 = make_uint4(0, 0, 0, 0); pv1 = pv0;
            if (pix < NPIX) {
                const ushort_t* s = CATn + ((size_t)slot * NPIX + pix) * 128 + c0 + spart * 16;
                pv0 = *(const uint4*)s;
                pv1 = *(const uint4*)(s + 8);
            }
        }
        const bf16x8 a0 = *(const bf16x8*)(A0 + k0);
        const bf16x8 a1 = *(const bf16x8*)(A1 + k0);
#pragma unroll
        for (int bn = 0; bn < 4; ++bn) {
            const bf16x8 b = *(const bf16x8*)&Bs[wp * 64 + bn * 16 + l15][lg * 8];
            acc[0][bn] = MFMA16(a0, b, acc[0][bn]);
            acc[1][bn] = MFMA16(a1, b, acc[1][bn]);
        }
        __syncthreads();
    }

    // epilogue: bias + relu + store
    const int obase = o0 + wo * 32 + lg * 4;
#pragma unroll
    for (int am = 0; am < 2; ++am) {
        const float4 bi = *(const float4*)&bout[obase + am * 16];
#pragma unroll
        for (int bn = 0; bn < 4; ++bn) {
            const int pix = pix0 + wp * 64 + bn * 16 + l15;
            if (pix < NPIX) {
                float* dst = out + ((size_t)n * O2 + obase + am * 16) * NPIX + pix;
                dst[0 * (size_t)NPIX] = fmaxf(acc[am][bn][0] + bi.x, 0.f);
                dst[1 * (size_t)NPIX] = fmaxf(acc[am][bn][1] + bi.y, 0.f);
                dst[2 * (size_t)NPIX] = fmaxf(acc[am][bn][2] + bi.z, 0.f);
                dst[3 * (size_t)NPIX] = fmaxf(acc[am][bn][3] + bi.w, 0.f);
            }
        }
    }
}

// ---------------------------------------------------------------------------
extern "C" void kernel_launch(void* const* d_in, const int* in_sizes, int n_in,
                              void* d_out, int out_size, void* d_ws, size_t ws_size,
                              hipStream_t stream) {
    const float* feature = (const float*)d_in[0];   // [2,256,100,100]
    const float* boxes   = (const float*)d_in[1];   // [2,10000,4]
    // d_in[2] = wh (unused by the reference)
    const float* w_cur   = (const float*)d_in[3];   // [128,256]
    // d_in[4] = b_cur  (cancelled by instance norm)
    const float* w_ltrb  = (const float*)d_in[5];   // [512,256]
    // d_in[6] = b_ltrb (cancelled by instance norm)
    const float* w_out   = (const float*)d_in[7];   // [256,640]
    const float* b_out   = (const float*)d_in[8];   // [256]
    float* out = (float*)d_out;

    float* ws = (float*)d_ws;
    float*    st     = ws;                                      // 2,560 f
    float2*   MS     = (float2*)(st + NB * CH1 * 2);            // 1,280 float2
    ushort_t* featTb = (ushort_t*)(MS + NB * CH1);              // 5,120,000 u16
    ushort_t* rawT   = featTb + (size_t)NB * NPIX * CIN;        // 12,800,000 u16
    ushort_t* CATb   = rawT + (size_t)NB * NPIX * CH1;          // 12,800,000 u16
    ushort_t* W1b    = CATb + (size_t)NB * 5 * NPIX * 128;      // 163,840 u16
    ushort_t* W2b    = W1b + CH1 * CIN;                         // 163,840 u16
    int*      OFFS   = (int*)(W2b + O2 * K2);                   // 880,000 i32
    float4*   WTS    = (float4*)(OFFS + NB * NM * NSAMP);       // 880,000 f4

    hipMemsetAsync(st, 0, (size_t)NB * CH1 * 2 * sizeof(float), stream);
    prep_k<<<(CH1 * CIN + O2 * K2 + 255) / 256, 256, 0, stream>>>(w_cur, w_ltrb, w_out, W1b, W2b);
    featT_k<<<dim3((NPIX + 63) / 64, 2, NB), 256, 0, stream>>>(feature, featTb);
    gemm1T_k<<<dim3((NPIX + 127) / 128, CH1 / 128, NB), 256, 0, stream>>>(featTb, W1b, rawT, st);
    stfin_k<<<(NB * CH1 + 255) / 256, 256, 0, stream>>>(st, MS);
    norm4_k<<<(NB * NPIX * 16 + 255) / 256, 256, 0, stream>>>(rawT, MS, CATb);
    coord_k<<<(NB * NM * NSAMP + 255) / 256, 256, 0, stream>>>(boxes, OFFS, WTS);
    borderN_k<<<NB * 4 * NPIX / 8, 256, 0, stream>>>(OFFS, WTS, rawT, MS, CATb);
    gemm2_k<<<dim3((NPIX + 127) / 128, O2 / 64, NB), 256, 0, stream>>>(W2b, CATb, b_out, out);
}

// Round 8
// 221.830 us; speedup vs baseline: 2.8505x; 1.1145x over previous
//
#include <hip/hip_runtime.h>
#include <hip/hip_bf16.h>
#include <math.h>

// Problem constants
#define NB    2
#define CIN   256
#define CB    128
#define HH    100
#define WW    100
#define NPIX  10000       // H*W
#define CH1   640         // 128 (cur) + 512 (ltrb)
#define K2    640         // final GEMM K
#define O2    256         // final GEMM M (output channels)
#define NM    40000       // 4 * NPIX  (flattened (box,border) units per n)
#define NSAMP 11          // POOL+1 samples per border

typedef __attribute__((ext_vector_type(8))) short bf16x8;   // 8 bf16 = 4 VGPR
typedef __attribute__((ext_vector_type(4))) float f32x4;    // MFMA accumulator
typedef unsigned short ushort_t;

__device__ __forceinline__ unsigned short f2bf(float f) {   // RNE f32->bf16
    unsigned u = __float_as_uint(f);
    u += 0x7FFF + ((u >> 16) & 1);
    return (unsigned short)(u >> 16);
}
__device__ __forceinline__ float bf2f(ushort_t u) {
    return __uint_as_float(((unsigned)u) << 16);
}

#define MFMA16(a, b, c) __builtin_amdgcn_mfma_f32_16x16x32_bf16((a), (b), (c), 0, 0, 0)

// ---------------------------------------------------------------------------
// prep_k: weights -> bf16. W1b[640][256] = {wcur;wltrb}. W2b[256][640] with the
// torch permute+reshape channel shuffle folded into the K index.
// ---------------------------------------------------------------------------
__global__ __launch_bounds__(256) void prep_k(const float* __restrict__ wcur,
                                              const float* __restrict__ wltrb,
                                              const float* __restrict__ wout,
                                              ushort_t* __restrict__ W1b,
                                              ushort_t* __restrict__ W2b) {
    int id = blockIdx.x * 256 + threadIdx.x;
    if (id < CH1 * CIN) {
        const int ch = id / CIN;
        const float v = (ch < CB) ? wcur[id] : wltrb[id - CB * CIN];
        W1b[id] = f2bf(v);
        return;
    }
    id -= CH1 * CIN;
    if (id < O2 * K2) {
        const int o = id / K2, k = id % K2;
        const int korig = (k < 512) ? ((k & 127) * 4 + (k >> 7)) : k;
        W2b[id] = f2bf(wout[(size_t)o * K2 + korig]);
    }
}

// ---------------------------------------------------------------------------
// featT_k: feature fp32 [n][c][pix] -> bf16 channel-last [n][pix][256].
// ---------------------------------------------------------------------------
__global__ __launch_bounds__(256) void featT_k(const float* __restrict__ feat,
                                               ushort_t* __restrict__ featTb) {
    __shared__ float T[128][65];
    const int pix0 = blockIdx.x * 64;
    const int ch0  = blockIdx.y * 128;
    const int n    = blockIdx.z;
    const int tid  = threadIdx.x;
    {
        const int pl = tid & 63, cl0 = tid >> 6;
#pragma unroll
        for (int i = 0; i < 32; ++i) {
            const int cl = cl0 + i * 4;
            const int pix = pix0 + pl;
            T[cl][pl] = (pix < NPIX)
                ? feat[((size_t)n * CIN + ch0 + cl) * NPIX + pix] : 0.f;
        }
    }
    __syncthreads();
    const int cl = tid & 127, pl0 = tid >> 7;
#pragma unroll
    for (int j = 0; j < 32; ++j) {
        const int pp = pl0 + j * 2;
        const int pix = pix0 + pp;
        if (pix < NPIX)
            featTb[((size_t)n * NPIX + pix) * CIN + ch0 + cl] = f2bf(T[cl][pp]);
    }
}

// ---------------------------------------------------------------------------
// GEMM1T (MFMA bf16, channel-last output), double-chunk staging:
//   rawT[n][pix][ch] = sum_c feat[n][pix][c] * W1[ch][c]    (bf16 store)
// Tile 128pix x 128ch, 4 waves, per-wave 64x64. K staged 64 per barrier-pair
// (2x 32-k LDS buffers, same k order -> bit-identical accumulation).
// Epilogue: fused instance-norm sum/sumsq + atomics.
// ---------------------------------------------------------------------------
__global__ __launch_bounds__(256) void gemm1T_k(const ushort_t* __restrict__ featTb,
                                                const ushort_t* __restrict__ W1b,
                                                ushort_t* __restrict__ rawT,
                                                float* __restrict__ st) {
    __shared__ ushort_t Bs[2][128][40];
    const int pix0 = blockIdx.x * 128;
    const int ch0  = blockIdx.y * 128;
    const int n    = blockIdx.z;
    const int tid  = threadIdx.x;
    const int lane = tid & 63, wv = tid >> 6;
    const int wp = wv & 1, wc = wv >> 1;          // pix half / ch half
    const int l15 = lane & 15, lg = lane >> 4;

    f32x4 acc[4][4];                              // [am(pix)][bn(ch)]
#pragma unroll
    for (int am = 0; am < 4; ++am)
#pragma unroll
        for (int bn = 0; bn < 4; ++bn)
#pragma unroll
            for (int r = 0; r < 4; ++r) acc[am][bn][r] = 0.f;

    const int srow = tid >> 1, spart = tid & 1;
    const int spix = pix0 + srow;
    const ushort_t* Bsrc  = featTb + (size_t)n * NPIX * CIN;
    const ushort_t* Wbase = W1b + (size_t)(ch0 + wc * 64 + l15) * CIN + lg * 8;

    uint4 pv0, pv1, pv2, pv3;
    {   // prologue: stage k 0..63 into regs
        pv0 = make_uint4(0, 0, 0, 0); pv1 = pv0; pv2 = pv0; pv3 = pv0;
        if (spix < NPIX) {
            const ushort_t* s = Bsrc + (size_t)spix * CIN + spart * 16;
            pv0 = *(const uint4*)s;       pv1 = *(const uint4*)(s + 8);
            pv2 = *(const uint4*)(s + 32); pv3 = *(const uint4*)(s + 40);
        }
    }
#pragma unroll
    for (int ks = 0; ks < CIN / 64; ++ks) {
        *(uint4*)&Bs[0][srow][spart * 16]     = pv0;
        *(uint4*)&Bs[0][srow][spart * 16 + 8] = pv1;
        *(uint4*)&Bs[1][srow][spart * 16]     = pv2;
        *(uint4*)&Bs[1][srow][spart * 16 + 8] = pv3;
        __syncthreads();
        if (ks + 1 < CIN / 64) {   // prefetch next 64-k (hidden under MFMA)
            pv0 = make_uint4(0, 0, 0, 0); pv1 = pv0; pv2 = pv0; pv3 = pv0;
            if (spix < NPIX) {
                const ushort_t* s = Bsrc + (size_t)spix * CIN + (ks + 1) * 64 + spart * 16;
                pv0 = *(const uint4*)s;       pv1 = *(const uint4*)(s + 8);
                pv2 = *(const uint4*)(s + 32); pv3 = *(const uint4*)(s + 40);
            }
        }
#pragma unroll
        for (int half = 0; half < 2; ++half) {
            const int k0 = ks * 64 + half * 32;
            bf16x8 bfrag[4];
#pragma unroll
            for (int bn = 0; bn < 4; ++bn)
                bfrag[bn] = *(const bf16x8*)(Wbase + (size_t)bn * 16 * CIN + k0);
#pragma unroll
            for (int am = 0; am < 4; ++am) {
                const bf16x8 a = *(const bf16x8*)&Bs[half][wp * 64 + am * 16 + l15][lg * 8];
#pragma unroll
                for (int bn = 0; bn < 4; ++bn)
                    acc[am][bn] = MFMA16(a, bfrag[bn], acc[am][bn]);
            }
        }
        __syncthreads();
    }

    // ---- fused instance-norm stats (pad pixels staged as 0 -> contribute 0) ----
#pragma unroll
    for (int bn = 0; bn < 4; ++bn) {
        float s = 0.f, q = 0.f;
#pragma unroll
        for (int am = 0; am < 4; ++am)
#pragma unroll
            for (int r = 0; r < 4; ++r) { const float v = acc[am][bn][r]; s += v; q += v * v; }
        s += __shfl_xor(s, 16); q += __shfl_xor(q, 16);
        s += __shfl_xor(s, 32); q += __shfl_xor(q, 32);
        if (lg == 0) {
            const int ch = ch0 + wc * 64 + bn * 16 + l15;
            atomicAdd(&st[(size_t)(n * CH1 + ch) * 2],     s);
            atomicAdd(&st[(size_t)(n * CH1 + ch) * 2 + 1], q);
        }
    }

    // store rawT bf16 channel-last
#pragma unroll
    for (int am = 0; am < 4; ++am)
#pragma unroll
        for (int r = 0; r < 4; ++r) {
            const int pix = pix0 + wp * 64 + am * 16 + lg * 4 + r;
            if (pix < NPIX) {
                ushort_t* dst = rawT + (size_t)(n * NPIX + pix) * CH1 + ch0 + wc * 64 + l15;
#pragma unroll
                for (int bn = 0; bn < 4; ++bn) dst[bn * 16] = f2bf(acc[am][bn][r]);
            }
        }
}

// ---------------------------------------------------------------------------
// stfin_k: finalize per-(n,ch) mean / rstd. MS[n*CH1+ch] = {m, rstd}.
// ---------------------------------------------------------------------------
__global__ __launch_bounds__(256) void stfin_k(const float* __restrict__ st,
                                               float2* __restrict__ MS) {
    const int ch = blockIdx.x * 256 + threadIdx.x;
    if (ch >= NB * CH1) return;
    const float sum = st[(size_t)ch * 2];
    const float sq  = st[(size_t)ch * 2 + 1];
    const float m   = sum * (1.0f / (float)NPIX);
    const float var = fmaxf(sq * (1.0f / (float)NPIX) - m * m, 0.f);
    MS[ch] = make_float2(m, 1.0f / sqrtf(var + 1e-5f));
}

// ---------------------------------------------------------------------------
// normAll_k: stream rawT, normalize+relu ALL 640 channels:
//   ch in [0,128)   -> CATb slot 4 (bf16)
//   ch in [128,640) -> Lb[n][b][pix][128] bf16 NORMALIZED (slice-major)
// Pure streaming, 8 ch per thread, no LDS.
// ---------------------------------------------------------------------------
__global__ __launch_bounds__(256) void normAll_k(const ushort_t* __restrict__ rawT,
                                                 const float2* __restrict__ MS,
                                                 ushort_t* __restrict__ CATb,
                                                 ushort_t* __restrict__ Lb) {
    const int id = blockIdx.x * 256 + threadIdx.x;   // (n*NPIX+pix)*80 + c8grp
    if (id >= NB * NPIX * 80) return;
    const int c8 = (id % 80) * 8;
    const int np = id / 80;                          // n*NPIX + pix
    const int n = np / NPIX, pix = np % NPIX;
    const uint4 v = *(const uint4*)(rawT + (size_t)np * CH1 + c8);
    ushort_t tmp[8]; *(uint4*)tmp = v;
    ushort_t outv[8];
    const float2* msb = MS + n * CH1 + c8;
#pragma unroll
    for (int j = 0; j < 8; ++j) {
        const float2 ms = msb[j];
        const float x = (bf2f(tmp[j]) - ms.x) * ms.y;
        outv[j] = f2bf(fmaxf(x, 0.f));
    }
    ushort_t* dst;
    if (c8 < 128) {
        dst = CATb + ((size_t)(n * 5 + 4) * NPIX + pix) * 128 + c8;
    } else {
        const int b  = (c8 - 128) >> 7;
        const int cc = (c8 - 128) & 127;
        dst = Lb + ((size_t)((n * 4 + b) * NPIX) + pix) * 128 + cc;
    }
    *(uint4*)dst = *(uint4*)outv;
}

// ---------------------------------------------------------------------------
// coord_k: one thread per (n, m=4p+b, sample k) -> bilinear descriptor
// (packed tap offset + valid-masked weights). Bit-identical coord math.
// Slice-major layout for XCD-affine border gather.
// ---------------------------------------------------------------------------
__global__ __launch_bounds__(256) void coord_k(const float* __restrict__ boxes,
                                               int* __restrict__ OFFS,
                                               float4* __restrict__ WTS) {
    const int id = blockIdx.x * 256 + threadIdx.x;
    if (id >= NB * NM * NSAMP) return;
    const int k  = id % NSAMP;
    const int mm = id / NSAMP;              // n*NM + m
    const int m  = mm % NM;
    const int n  = mm / NM;
    const int p = m >> 2, b = m & 3;
    const float* bx = boxes + ((size_t)n * NPIX + p) * 4;
    const float x1 = bx[0], y1 = bx[1], x2 = bx[2], y2 = bx[3];
    const float bw = __fsub_rn(x2, x1), bh = __fsub_rn(y2, y1);
    const float t = __fdiv_rn((float)k, 10.0f);
    float x, y;
    if (b == 0)      { x = __fadd_rn(x1, __fmul_rn(t, bw)); y = y1; }
    else if (b == 1) { x = x1; y = __fadd_rn(y1, __fmul_rn(t, bh)); }
    else if (b == 2) { x = __fadd_rn(x1, __fmul_rn(t, bw)); y = y2; }
    else             { x = x2; y = __fadd_rn(y1, __fmul_rn(t, bh)); }
    const bool valid = (x >= -1.f) && (x <= (float)WW) && (y >= -1.f) && (y <= (float)HH);
    x = fmaxf(x, 0.f); y = fmaxf(y, 0.f);
    const float x0f = floorf(x), y0f = floorf(y);
    const bool cx = (x0f >= (float)(WW - 1));
    const bool cy = (y0f >= (float)(HH - 1));
    const int ix0 = cx ? (WW - 1) : (int)x0f;
    const int iy0 = cy ? (HH - 1) : (int)y0f;
    const int ix1 = min(ix0 + 1, WW - 1);
    const int iy1 = min(iy0 + 1, HH - 1);
    const float lx = cx ? 0.f : __fsub_rn(x, (float)ix0);
    const float ly = cy ? 0.f : __fsub_rn(y, (float)iy0);
    const float hx = 1.f - lx, hy = 1.f - ly;
    const float vf = valid ? 1.f : 0.f;
    const int dx = ix1 - ix0, dy = iy1 - iy0;
    const int did = (((n * 4 + b) * NPIX) + p) * NSAMP + k;   // slice-major
    OFFS[did] = (iy0 * WW + ix0) | (dx << 14) | (dy << 15);
    WTS[did]  = make_float4((hy * hx) * vf, (hy * lx) * vf,
                            (ly * hx) * vf, (ly * lx) * vf);
}

// ---------------------------------------------------------------------------
// borderB_k: gather from pre-normalized bf16 Lb (taps need only weight+max).
// XCD-affine: slice s = blockIdx.x & 7 -> (n,b); 2.56 MB hot set per XCD L2.
// 16 units x 16 lanes (8 ch each, uint4 taps) per 256-thr block.
// ---------------------------------------------------------------------------
__global__ __launch_bounds__(256) void borderB_k(const int* __restrict__ OFFS,
                                                 const float4* __restrict__ WTS,
                                                 const ushort_t* __restrict__ Lb,
                                                 ushort_t* __restrict__ CATb) {
    const int s = blockIdx.x & 7;            // slice -> XCD affinity
    const int n = s >> 2, b = s & 3;
    const int u = threadIdx.x >> 4;          // unit in block: 0..15
    const int c8 = (threadIdx.x & 15) * 8;   // channel base
    const int p = (blockIdx.x >> 3) * 16 + u;
    const ushort_t* Lbase = Lb + ((size_t)(n * 4 + b) * NPIX) * 128 + c8;
    const int dbase = (((n * 4 + b) * NPIX) + p) * NSAMP;
    float a0 = -INFINITY, a1 = -INFINITY, a2 = -INFINITY, a3 = -INFINITY;
    float a4 = -INFINITY, a5 = -INFINITY, a6 = -INFINITY, a7 = -INFINITY;
#pragma unroll
    for (int k = 0; k < NSAMP; ++k) {
        const int    v  = OFFS[dbase + k];
        const float4 wt = WTS[dbase + k];
        const int off = v & 0x3FFF;
        const int dxo = ((v >> 14) & 1) * 128;
        const int dyo = ((v >> 15) & 1) * (WW * 128);
        const ushort_t* t = Lbase + (size_t)off * 128;
        ushort_t g00[8], g01[8], g10[8], g11[8];
        *(uint4*)g00 = *(const uint4*)(t);
        *(uint4*)g01 = *(const uint4*)(t + dxo);
        *(uint4*)g10 = *(const uint4*)(t + dyo);
        *(uint4*)g11 = *(const uint4*)(t + dyo + dxo);
#define TAPJ(j, accv)                                                        \
        {                                                                    \
            float val = wt.x * bf2f(g00[j]);                                 \
            val = fmaf(wt.y, bf2f(g01[j]), val);                             \
            val = fmaf(wt.z, bf2f(g10[j]), val);                             \
            val = fmaf(wt.w, bf2f(g11[j]), val);                             \
            accv = fmaxf(accv, val);                                         \
        }
        TAPJ(0, a0) TAPJ(1, a1) TAPJ(2, a2) TAPJ(3, a3)
        TAPJ(4, a4) TAPJ(5, a5) TAPJ(6, a6) TAPJ(7, a7)
#undef TAPJ
    }
    const int m = p * 4 + b;
    ushort_t outv[8];
    outv[0] = f2bf(a0); outv[1] = f2bf(a1); outv[2] = f2bf(a2); outv[3] = f2bf(a3);
    outv[4] = f2bf(a4); outv[5] = f2bf(a5); outv[6] = f2bf(a6); outv[7] = f2bf(a7);
    *(uint4*)(CATb + ((size_t)n * 5 * NPIX + m) * 128 + c8) = *(uint4*)outv;
}

// ---------------------------------------------------------------------------
// GEMM2 (MFMA bf16, double-chunk staging): out = relu(bout + W2b x CATb).
// Block tile 64o x 128pix, K=640 staged 64 per barrier-pair.
// ---------------------------------------------------------------------------
__global__ __launch_bounds__(256) void gemm2_k(const ushort_t* __restrict__ W2b,
                                               const ushort_t* __restrict__ CATb,
                                               const float* __restrict__ bout,
                                               float* __restrict__ out) {
    __shared__ ushort_t Bs[2][128][40];
    const int pix0 = blockIdx.x * 128;
    const int o0   = blockIdx.y * 64;
    const int n    = blockIdx.z;
    const int tid  = threadIdx.x;
    const int lane = tid & 63, wv = tid >> 6;
    const int wo = wv & 1, wp = wv >> 1;
    const int l15 = lane & 15, lg = lane >> 4;

    f32x4 acc[2][4];
#pragma unroll
    for (int am = 0; am < 2; ++am)
#pragma unroll
        for (int bn = 0; bn < 4; ++bn)
#pragma unroll
            for (int r = 0; r < 4; ++r) acc[am][bn][r] = 0.f;

    const int srow = tid >> 1, spart = tid & 1;
    const int spix = pix0 + srow;
    const ushort_t* CATn = CATb + (size_t)n * 5 * NPIX * 128;
    const ushort_t* A0 = W2b + (size_t)(o0 + wo * 32 + l15) * K2 + lg * 8;
    const ushort_t* A1 = A0 + 16 * K2;

    // 32-k chunk j: slot = j>>2, c0 = (j&3)*32
#define G2ADDR(j) (CATn + ((size_t)((j) >> 2) * NPIX + spix) * 128 + (((j) & 3) * 32) + spart * 16)

    uint4 pv0, pv1, pv2, pv3;
    {   // prologue: chunks 0,1
        pv0 = make_uint4(0, 0, 0, 0); pv1 = pv0; pv2 = pv0; pv3 = pv0;
        if (spix < NPIX) {
            const ushort_t* s0 = G2ADDR(0);
            const ushort_t* s1 = G2ADDR(1);
            pv0 = *(const uint4*)s0; pv1 = *(const uint4*)(s0 + 8);
            pv2 = *(const uint4*)s1; pv3 = *(const uint4*)(s1 + 8);
        }
    }
#pragma unroll
    for (int ks = 0; ks < K2 / 64; ++ks) {
        *(uint4*)&Bs[0][srow][spart * 16]     = pv0;
        *(uint4*)&Bs[0][srow][spart * 16 + 8] = pv1;
        *(uint4*)&Bs[1][srow][spart * 16]     = pv2;
        *(uint4*)&Bs[1][srow][spart * 16 + 8] = pv3;
        __syncthreads();
        if (ks + 1 < K2 / 64) {   // prefetch next two chunks
            pv0 = make_uint4(0, 0, 0, 0); pv1 = pv0; pv2 = pv0; pv3 = pv0;
            if (spix < NPIX) {
                const ushort_t* s0 = G2ADDR(2 * ks + 2);
                const ushort_t* s1 = G2ADDR(2 * ks + 3);
                pv0 = *(const uint4*)s0; pv1 = *(const uint4*)(s0 + 8);
                pv2 = *(const uint4*)s1; pv3 = *(const uint4*)(s1 + 8);
            }
        }
#pragma unroll
        for (int half = 0; half < 2; ++half) {
            const int k0 = ks * 64 + half * 32;
            const bf16x8 af0 = *(const bf16x8*)(A0 + k0);
            const bf16x8 af1 = *(const bf16x8*)(A1 + k0);
#pragma unroll
            for (int bn = 0; bn < 4; ++bn) {
                const bf16x8 bfr = *(const bf16x8*)&Bs[half][wp * 64 + bn * 16 + l15][lg * 8];
                acc[0][bn] = MFMA16(af0, bfr, acc[0][bn]);
                acc[1][bn] = MFMA16(af1, bfr, acc[1][bn]);
            }
        }
        __syncthreads();
    }
#undef G2ADDR

    // epilogue: bias + relu + store
    const int obase = o0 + wo * 32 + lg * 4;
#pragma unroll
    for (int am = 0; am < 2; ++am) {
        const float4 bi = *(const float4*)&bout[obase + am * 16];
#pragma unroll
        for (int bn = 0; bn < 4; ++bn) {
            const int pix = pix0 + wp * 64 + bn * 16 + l15;
            if (pix < NPIX) {
                float* dst = out + ((size_t)n * O2 + obase + am * 16) * NPIX + pix;
                dst[0 * (size_t)NPIX] = fmaxf(acc[am][bn][0] + bi.x, 0.f);
                dst[1 * (size_t)NPIX] = fmaxf(acc[am][bn][1] + bi.y, 0.f);
                dst[2 * (size_t)NPIX] = fmaxf(acc[am][bn][2] + bi.z, 0.f);
                dst[3 * (size_t)NPIX] = fmaxf(acc[am][bn][3] + bi.w, 0.f);
            }
        }
    }
}

// ---------------------------------------------------------------------------
extern "C" void kernel_launch(void* const* d_in, const int* in_sizes, int n_in,
                              void* d_out, int out_size, void* d_ws, size_t ws_size,
                              hipStream_t stream) {
    const float* feature = (const float*)d_in[0];   // [2,256,100,100]
    const float* boxes   = (const float*)d_in[1];   // [2,10000,4]
    // d_in[2] = wh (unused by the reference)
    const float* w_cur   = (const float*)d_in[3];   // [128,256]
    // d_in[4] = b_cur  (cancelled by instance norm)
    const float* w_ltrb  = (const float*)d_in[5];   // [512,256]
    // d_in[6] = b_ltrb (cancelled by instance norm)
    const float* w_out   = (const float*)d_in[7];   // [256,640]
    const float* b_out   = (const float*)d_in[8];   // [256]
    float* out = (float*)d_out;

    float* ws = (float*)d_ws;
    float*    st     = ws;                                      // 2,560 f
    float2*   MS     = (float2*)(st + NB * CH1 * 2);            // 1,280 float2
    ushort_t* featTb = (ushort_t*)(MS + NB * CH1);              // 5,120,000 u16
    ushort_t* rawT   = featTb + (size_t)NB * NPIX * CIN;        // 12,800,000 u16
    ushort_t* CATb   = rawT + (size_t)NB * NPIX * CH1;          // 12,800,000 u16
    ushort_t* Lb     = CATb + (size_t)NB * 5 * NPIX * 128;      // 10,240,000 u16
    ushort_t* W1b    = Lb + (size_t)NB * 4 * NPIX * 128;        // 163,840 u16
    ushort_t* W2b    = W1b + CH1 * CIN;                         // 163,840 u16
    int*      OFFS   = (int*)(W2b + O2 * K2);                   // 880,000 i32
    float4*   WTS    = (float4*)(OFFS + NB * NM * NSAMP);       // 880,000 f4

    hipMemsetAsync(st, 0, (size_t)NB * CH1 * 2 * sizeof(float), stream);
    prep_k<<<(CH1 * CIN + O2 * K2 + 255) / 256, 256, 0, stream>>>(w_cur, w_ltrb, w_out, W1b, W2b);
    featT_k<<<dim3((NPIX + 63) / 64, 2, NB), 256, 0, stream>>>(feature, featTb);
    gemm1T_k<<<dim3((NPIX + 127) / 128, CH1 / 128, NB), 256, 0, stream>>>(featTb, W1b, rawT, st);
    stfin_k<<<(NB * CH1 + 255) / 256, 256, 0, stream>>>(st, MS);
    normAll_k<<<(NB * NPIX * 80 + 255) / 256, 256, 0, stream>>>(rawT, MS, CATb, Lb);
    coord_k<<<(NB * NM * NSAMP + 255) / 256, 256, 0, stream>>>(boxes, OFFS, WTS);
    borderB_k<<<NB * 4 * NPIX / 16, 256, 0, stream>>>(OFFS, WTS, Lb, CATb);
    gemm2_k<<<dim3((NPIX + 127) / 128, O2 / 64, NB), 256, 0, stream>>>(W2b, CATb, b_out, out);
}